// Round 1
// baseline (222.312 us; speedup 1.0000x reference)
//
#include <hip/hip_runtime.h>

// FullAttention fused block on gfx950. fp32 harness I/O, fp16 MFMA internally
// (f16 chosen over bf16: single-instruction f32<->f16 converts + 10-bit mantissa).
//
// Pipeline:
//   k_cvt     : w_qkv, w_out fp32 -> f16
//   k_rmsnorm : x[C][N] -> xn[C][N] fp32 (residual) + xnT[N][C] f16
//   k_qkv     : GEMM 1536x256x4096 -> qT/kT [head][p][d] f16 (q pre-scaled by
//               0.125*log2e), vv [d'][p] f16
//   k_attn    : flash attention, no-max softmax (scores O(0.3)), S^T/O^T
//               orientation, 32 q/wave x 4-way key split, packed-dword P
//               transpose via 4 shuffles, lsum via ones-MFMA.
//               32 q/wave (not 64): halves merge LDS to ~36 KB and halves
//               accumulator VGPRs -> 4 blocks/CU, 16 waves/CU (was 8) to hide
//               the S-MFMA->exp2->bpermute->PV-MFMA serial chain.
//   k_oproj   : GEMM 256x512x4096 + bias + residual -> fp32 out
//
// MFMA 16x16x32 layouts (HW-verified per guide):
//   A-frag: lane holds A[m=lane&15][k=quad*8+j], j=0..7
//   B-frag: lane holds B[k=quad*8+j][n=lane&15]
//   C/D   : lane holds D[row=quad*4+reg][col=lane&15], reg=0..3

#define NPIX 4096
#define CIN 256
#define INNER 512
#define NHEAD 8
#define DH 64

typedef _Float16 f16;
typedef __attribute__((ext_vector_type(8))) _Float16 f16x8;
typedef __attribute__((ext_vector_type(4))) float f32x4;

static __device__ __forceinline__ f32x4 mfma_f16(f16x8 a, f16x8 b, f32x4 c) {
  return __builtin_amdgcn_mfma_f32_16x16x32_f16(a, b, c, 0, 0, 0);
}

static __device__ __forceinline__ unsigned pk2(float lo, float hi) {
  return __builtin_bit_cast(unsigned, __builtin_amdgcn_cvt_pkrtz(lo, hi));
}

// ---------------- K0: fp32 -> f16 ----------------
__global__ __launch_bounds__(256) void k_cvt(const float* __restrict__ a,
                                             f16* __restrict__ b, int n) {
  int i = blockIdx.x * 256 + threadIdx.x;
  if (i < n) b[i] = (f16)a[i];
}

// ---------------- K1: RMSNorm (256 blocks, 16 pixels each) ----------------
__global__ __launch_bounds__(256) void k_rmsnorm(const float* __restrict__ x,
                                                 const float* __restrict__ w,
                                                 float* __restrict__ xn,
                                                 f16* __restrict__ xnT) {
  const int pi = threadIdx.x & 15, cs = threadIdx.x >> 4;
  const int p = blockIdx.x * 16 + pi;
  __shared__ float red[16][16];
  float ss = 0.f;
  for (int i = 0; i < 16; ++i) {
    float v = x[(cs * 16 + i) * NPIX + p];
    ss += v * v;
  }
  red[cs][pi] = ss;
  __syncthreads();
  float tot = 0.f;
#pragma unroll
  for (int s = 0; s < 16; ++s) tot += red[s][pi];
  float inv = 16.0f / fmaxf(sqrtf(tot), 1e-12f);  // sqrt(256)=16
  for (int i = 0; i < 16; ++i) {
    int c = cs * 16 + i;
    float v = x[c * NPIX + p] * inv * w[c];
    xn[c * NPIX + p] = v;
    xnT[p * CIN + c] = (f16)v;
  }
}

// ---------------- K2: QKV GEMM, wave tile 32x64 ----------------
// grid (32, 24). Sections 0/1 (q,k) compute D=[p][o] (swapped operands) so the
// [head][p][d] store is 16-lane-contiguous; section 2 (v) computes D=[o][p].
// Section 0 (q) is pre-scaled by 0.125*log2(e) so attn uses exp2(s) directly.
__global__ __launch_bounds__(256) void k_qkv(const f16* __restrict__ wqkv,
                                             const f16* __restrict__ xnT,
                                             f16* __restrict__ qT,
                                             f16* __restrict__ kT,
                                             f16* __restrict__ vv) {
  const int lane = threadIdx.x & 63, wave = threadIdx.x >> 6;
  const int l15 = lane & 15, quad = lane >> 4;
  const int obase = blockIdx.y * 64 + (wave >> 1) * 32;
  const int pbase = blockIdx.x * 128 + (wave & 1) * 64;
  const int sect = blockIdx.y >> 3;  // 0=q, 1=k, 2=v
  f32x4 acc[8];
#pragma unroll
  for (int i = 0; i < 8; ++i) acc[i] = (f32x4){0.f, 0.f, 0.f, 0.f};
#pragma unroll
  for (int kc = 0; kc < CIN / 32; ++kc) {
    f16x8 af[2], bfr[4];
#pragma unroll
    for (int oc = 0; oc < 2; ++oc)
      af[oc] = *(const f16x8*)(wqkv + (size_t)(obase + oc * 16 + l15) * CIN + kc * 32 + quad * 8);
#pragma unroll
    for (int pc = 0; pc < 4; ++pc)
      bfr[pc] = *(const f16x8*)(xnT + (size_t)(pbase + pc * 16 + l15) * CIN + kc * 32 + quad * 8);
    if (sect < 2) {
#pragma unroll
      for (int pc = 0; pc < 4; ++pc)
#pragma unroll
        for (int oc = 0; oc < 2; ++oc)
          acc[pc * 2 + oc] = mfma_f16(bfr[pc], af[oc], acc[pc * 2 + oc]);
    } else {
#pragma unroll
      for (int oc = 0; oc < 2; ++oc)
#pragma unroll
        for (int pc = 0; pc < 4; ++pc)
          acc[oc * 4 + pc] = mfma_f16(af[oc], bfr[pc], acc[oc * 4 + pc]);
    }
  }
  if (sect < 2) {
    f16* dst = (sect == 0) ? qT : kT;
    const float sc = (sect == 0) ? 0.18033688f : 1.0f;  // 0.125*log2(e)
    const int head = blockIdx.y & 7;
    const int dd = (wave >> 1) * 32;
#pragma unroll
    for (int pc = 0; pc < 4; ++pc)
#pragma unroll
      for (int oc = 0; oc < 2; ++oc)
#pragma unroll
        for (int r = 0; r < 4; ++r) {
          int p = pbase + pc * 16 + quad * 4 + r;
          dst[((size_t)(head << 12) + p) * DH + dd + oc * 16 + l15] =
              (f16)(acc[pc * 2 + oc][r] * sc);
        }
  } else {
#pragma unroll
    for (int oc = 0; oc < 2; ++oc)
#pragma unroll
      for (int r = 0; r < 4; ++r) {
        int o = obase + oc * 16 + quad * 4 + r - 2 * INNER;
#pragma unroll
        for (int pc = 0; pc < 4; ++pc)
          vv[(size_t)o * NPIX + pbase + pc * 16 + l15] = (f16)acc[oc * 4 + pc][r];
      }
  }
}

// ---------------- K3: flash attention ----------------
// grid (128, 8): block = (head, 32 queries); wave w owns keys [w*1024,(w+1)*1024).
// Per 32-key iteration: 8 S-MFMAs + 10 PV/lsum-MFMAs, K/V frags reused x2.
// LDS merge buffer ~36 KB -> 4 blocks/CU; launch_bounds(256,4) caps VGPR at 128
// so all 16 waves/CU are resident (latency hiding for exp2/bpermute chains).
__global__ __launch_bounds__(256, 4) void k_attn(const f16* __restrict__ qT,
                                                 const f16* __restrict__ kT,
                                                 const f16* __restrict__ vv,
                                                 f16* __restrict__ Ows) {
  const int head = blockIdx.y;
  const int tid = threadIdx.x;
  const int wave = tid >> 6, lane = tid & 63;
  const int l15 = lane & 15, quad = lane >> 4;
  const int qb = blockIdx.x * 32;

  __shared__ float Om[4][2][64][17];  // [wave][qt][d][q]
  __shared__ float Ll[4][2][16];      // [wave][qt][q]

  // Q B-frags: B[k=d][n=q] from qT[head][q][d]
  f16x8 qf[2][2];
#pragma unroll
  for (int qt = 0; qt < 2; ++qt)
#pragma unroll
    for (int kc = 0; kc < 2; ++kc)
      qf[qt][kc] = *(const f16x8*)(qT + ((size_t)(head << 12) + qb + qt * 16 + l15) * DH + kc * 32 + quad * 8);

  f32x4 o[2][4], ol[2];
#pragma unroll
  for (int qt = 0; qt < 2; ++qt) {
#pragma unroll
    for (int c = 0; c < 4; ++c) o[qt][c] = (f32x4){0.f, 0.f, 0.f, 0.f};
    ol[qt] = (f32x4){0.f, 0.f, 0.f, 0.f};
  }

  const f16* kbase = kT + (size_t)(head << 12) * DH;
  const f16* vbase = vv + (size_t)(head * DH) * NPIX;
  const int kb0 = wave * (NPIX / 4);
  const int srcA = ((quad & 1) << 5) + l15;  // P^T permute source lanes
  const int srcB = srcA + 16;
  const bool hiQuad = quad >= 2;             // nc half select
  const f16x8 onesv = {1.f16, 1.f16, 1.f16, 1.f16, 1.f16, 1.f16, 1.f16, 1.f16};

  // prefetch K for first tile
  f16x8 kf[2][2], kfn[2][2];
#pragma unroll
  for (int nc = 0; nc < 2; ++nc)
#pragma unroll
    for (int kc = 0; kc < 2; ++kc)
      kf[nc][kc] = *(const f16x8*)(kbase + (size_t)(kb0 + nc * 16 + l15) * DH + kc * 32 + quad * 8);

  for (int it = 0; it < 32; ++it) {
    const int kb = kb0 + it * 32;
    // V loads for current tile (consumed after softmax)
    f16x8 vf[4];
#pragma unroll
    for (int c = 0; c < 4; ++c)
      vf[c] = *(const f16x8*)(vbase + (size_t)(c * 16 + l15) * NPIX + kb + quad * 8);
    // K prefetch for next tile
    const int kbn = kb0 + ((it + 1) & 31) * 32;
#pragma unroll
    for (int nc = 0; nc < 2; ++nc)
#pragma unroll
      for (int kc = 0; kc < 2; ++kc)
        kfn[nc][kc] = *(const f16x8*)(kbase + (size_t)(kbn + nc * 16 + l15) * DH + kc * 32 + quad * 8);

    // S^T[key][q] = K @ Q'^T (q pre-scaled; C-layout row=key, col=q)
    f32x4 s[2][2];
#pragma unroll
    for (int qt = 0; qt < 2; ++qt)
#pragma unroll
      for (int nc = 0; nc < 2; ++nc) {
        s[qt][nc] = mfma_f16(kf[nc][0], qf[qt][0], (f32x4){0.f, 0.f, 0.f, 0.f});
        s[qt][nc] = mfma_f16(kf[nc][1], qf[qt][1], s[qt][nc]);
      }

#pragma unroll
    for (int qt = 0; qt < 2; ++qt) {
      // p = exp2(s'), no max subtraction (|s'| << 1)
      float p0[4], p1[4];
#pragma unroll
      for (int r = 0; r < 4; ++r) {
        p0[r] = __builtin_amdgcn_exp2f(s[qt][0][r]);
        p1[r] = __builtin_amdgcn_exp2f(s[qt][1][r]);
      }
      // P^T C-layout -> B-frag: pack (r,r+1) pairs, 4 whole-dword shuffles.
      // dst lane (quad,l15): keys quad*8+j; nc=quad>>1, src quads 2*(quad&1),+1.
      unsigned A0 = pk2(p0[0], p0[1]), B0 = pk2(p0[2], p0[3]);
      unsigned A1 = pk2(p1[0], p1[1]), B1 = pk2(p1[2], p1[3]);
      unsigned As = hiQuad ? A1 : A0;
      unsigned Bs = hiQuad ? B1 : B0;
      union { f16x8 v; unsigned u[4]; } pf;
      pf.u[0] = (unsigned)__shfl((int)As, srcA);
      pf.u[1] = (unsigned)__shfl((int)Bs, srcA);
      pf.u[2] = (unsigned)__shfl((int)As, srcB);
      pf.u[3] = (unsigned)__shfl((int)Bs, srcB);
      // O^T[d][q] += V^T @ P^T ; row sums via ones-MFMA (idle MFMA pipe)
#pragma unroll
      for (int c = 0; c < 4; ++c) o[qt][c] = mfma_f16(vf[c], pf.v, o[qt][c]);
      ol[qt] = mfma_f16(onesv, pf.v, ol[qt]);
    }

    // rotate K buffers
#pragma unroll
    for (int nc = 0; nc < 2; ++nc)
#pragma unroll
      for (int kc = 0; kc < 2; ++kc) kf[nc][kc] = kfn[nc][kc];
  }

  // write per-wave partials; ol rows are all equal = per-q partial lsum
#pragma unroll
  for (int qt = 0; qt < 2; ++qt) {
    if (quad == 0) Ll[wave][qt][l15] = ol[qt][0];
#pragma unroll
    for (int c = 0; c < 4; ++c)
#pragma unroll
      for (int r = 0; r < 4; ++r)
        Om[wave][qt][c * 16 + quad * 4 + r][l15] = o[qt][c][r];
  }
  __syncthreads();

  // merge 4 key-splits (pure sums): thread t -> d = t&63, 4 q per qt
  const int d = tid & 63;
  const int qg = tid >> 6;
#pragma unroll
  for (int qt = 0; qt < 2; ++qt)
#pragma unroll
    for (int i = 0; i < 4; ++i) {
      int q = qg * 4 + i;
      float O = Om[0][qt][d][q] + Om[1][qt][d][q] + Om[2][qt][d][q] + Om[3][qt][d][q];
      float L = Ll[0][qt][q] + Ll[1][qt][q] + Ll[2][qt][q] + Ll[3][qt][q];
      Ows[((size_t)(head << 12) + qb + qt * 16 + q) * DH + d] = (f16)(O / L);
    }
}

// ---------------- K4: out projection + bias + residual ----------------
// grid (64, 8), wave tile 16x32
__global__ __launch_bounds__(256) void k_oproj(const f16* __restrict__ wout,
                                               const f16* __restrict__ Ows,
                                               const float* __restrict__ bout,
                                               const float* __restrict__ xn,
                                               float* __restrict__ out) {
  const int lane = threadIdx.x & 63, wave = threadIdx.x >> 6;
  const int l15 = lane & 15, quad = lane >> 4;
  const int mbase = blockIdx.y * 32 + (wave >> 1) * 16;
  const int pbase = blockIdx.x * 64 + (wave & 1) * 32;
  f32x4 acc[2];
  acc[0] = (f32x4){0.f, 0.f, 0.f, 0.f};
  acc[1] = (f32x4){0.f, 0.f, 0.f, 0.f};
#pragma unroll
  for (int kc = 0; kc < INNER / 32; ++kc) {
    f16x8 af = *(const f16x8*)(wout + (size_t)(mbase + l15) * INNER + kc * 32 + quad * 8);
    int i0 = kc * 32 + quad * 8;
    int head = i0 >> 6, d0 = i0 & 63;
#pragma unroll
    for (int pc = 0; pc < 2; ++pc) {
      f16x8 bfr = *(const f16x8*)(Ows + ((size_t)(head << 12) + pbase + pc * 16 + l15) * DH + d0);
      acc[pc] = mfma_f16(af, bfr, acc[pc]);
    }
  }
#pragma unroll
  for (int pc = 0; pc < 2; ++pc)
#pragma unroll
    for (int r = 0; r < 4; ++r) {
      int c = mbase + quad * 4 + r, p = pbase + pc * 16 + l15;
      out[c * NPIX + p] = acc[pc][r] + bout[c] + xn[c * NPIX + p];
    }
}

extern "C" void kernel_launch(void* const* d_in, const int* in_sizes, int n_in,
                              void* d_out, int out_size, void* d_ws, size_t ws_size,
                              hipStream_t stream) {
  (void)in_sizes; (void)n_in; (void)out_size; (void)ws_size;
  const float* x      = (const float*)d_in[0];
  const float* norm_w = (const float*)d_in[1];
  const float* w_qkv  = (const float*)d_in[2];
  const float* w_out  = (const float*)d_in[3];
  const float* b_out  = (const float*)d_in[4];
  float* out = (float*)d_out;

  char* ws = (char*)d_ws;
  float* xn    = (float*)(ws);                 // 4 MB
  f16* xnT     = (f16*)(ws + (4u << 20));      // 2 MB
  f16* qT      = (f16*)(ws + (6u << 20));      // 4 MB  [head][p][d], pre-scaled
  f16* kT      = (f16*)(ws + (10u << 20));     // 4 MB  [head][p][d]
  f16* vv      = (f16*)(ws + (14u << 20));     // 4 MB  [head*64+d][p]
  f16* Ows     = (f16*)(ws + (18u << 20));     // 4 MB  [head][p][d]
  f16* wqkv_h  = (f16*)(ws + (22u << 20));     // 0.75 MB
  f16* wout_h  = (f16*)(ws + (23u << 20));     // 0.25 MB

  hipLaunchKernelGGL(k_cvt, dim3((3 * INNER * CIN + 255) / 256), dim3(256), 0, stream,
                     w_qkv, wqkv_h, 3 * INNER * CIN);
  hipLaunchKernelGGL(k_cvt, dim3((CIN * INNER + 255) / 256), dim3(256), 0, stream,
                     w_out, wout_h, CIN * INNER);
  hipLaunchKernelGGL(k_rmsnorm, dim3(NPIX / 16), dim3(256), 0, stream, x, norm_w, xn, xnT);
  hipLaunchKernelGGL(k_qkv, dim3(NPIX / 128, 1536 / 64), dim3(256), 0, stream,
                     wqkv_h, xnT, qT, kT, vv);
  hipLaunchKernelGGL(k_attn, dim3(NPIX / 32, NHEAD), dim3(256), 0, stream,
                     qT, kT, vv, Ows);
  hipLaunchKernelGGL(k_oproj, dim3(NPIX / 64, CIN / 32), dim3(256), 0, stream,
                     wout_h, Ows, b_out, xn, out);
}

// Round 2
// 172.220 us; speedup vs baseline: 1.2909x; 1.2909x over previous
//
#include <hip/hip_runtime.h>

// FullAttention fused block on gfx950. fp32 harness I/O, fp16 MFMA internally.
//
// Pipeline:
//   k_cvt     : w_qkv, w_out fp32 -> f16
//   k_rmsnorm : x[C][N] -> xn[C][N] fp32 (residual) + xnT[N][C] f16 (vectorized
//               f16x8 stores)
//   k_qkv     : GEMM 1536x256x4096 -> qT/kT [head][p][d] f16 (q pre-scaled by
//               0.125*log2e), vv [d'][p] f16
//   k_attn    : flash attention. Round-1 A/B showed the kernel pins at
//               ~12.8 B/cyc/CU of vector-memory traffic regardless of
//               occupancy (L1-miss service bound), so minimize bytes/CU:
//               128 q per wave (2x reuse of K/V), 8-wave blocks sharing the
//               same 128 q with 8-way key split, head-per-XCD block swizzle
//               so each XCD's L2 holds exactly one head's K/V (1 MB).
//               lsum via VALU + shfl_xor (frees 24 VGPR vs ones-MFMA).
//   k_oproj   : GEMM 256x512x4096 + bias + residual -> fp32 out
//
// MFMA 16x16x32 layouts (HW-verified per guide):
//   A-frag: lane holds A[m=lane&15][k=quad*8+j], j=0..7
//   B-frag: lane holds B[k=quad*8+j][n=lane&15]
//   C/D   : lane holds D[row=quad*4+reg][col=lane&15], reg=0..3

#define NPIX 4096
#define CIN 256
#define INNER 512
#define NHEAD 8
#define DH 64

typedef _Float16 f16;
typedef __attribute__((ext_vector_type(8))) _Float16 f16x8;
typedef __attribute__((ext_vector_type(4))) float f32x4;

static __device__ __forceinline__ f32x4 mfma_f16(f16x8 a, f16x8 b, f32x4 c) {
  return __builtin_amdgcn_mfma_f32_16x16x32_f16(a, b, c, 0, 0, 0);
}

static __device__ __forceinline__ unsigned pk2(float lo, float hi) {
  return __builtin_bit_cast(unsigned, __builtin_amdgcn_cvt_pkrtz(lo, hi));
}

// ---------------- K0: fp32 -> f16 ----------------
__global__ __launch_bounds__(256) void k_cvt(const float* __restrict__ a,
                                             f16* __restrict__ b, int n) {
  int i = blockIdx.x * 256 + threadIdx.x;
  if (i < n) b[i] = (f16)a[i];
}

// ---------------- K1: RMSNorm (256 blocks, 16 pixels each) ----------------
__global__ __launch_bounds__(256) void k_rmsnorm(const float* __restrict__ x,
                                                 const float* __restrict__ w,
                                                 float* __restrict__ xn,
                                                 f16* __restrict__ xnT) {
  const int pi = threadIdx.x & 15, cs = threadIdx.x >> 4;
  const int p = blockIdx.x * 16 + pi;
  __shared__ float red[16][16];
  float xv[16];
  float ss = 0.f;
#pragma unroll
  for (int i = 0; i < 16; ++i) {
    xv[i] = x[(cs * 16 + i) * NPIX + p];
    ss += xv[i] * xv[i];
  }
  red[cs][pi] = ss;
  __syncthreads();
  float tot = 0.f;
#pragma unroll
  for (int s = 0; s < 16; ++s) tot += red[s][pi];
  float inv = 16.0f / fmaxf(sqrtf(tot), 1e-12f);  // sqrt(256)=16
  union { f16x8 v[2]; f16 h[16]; } hv;
#pragma unroll
  for (int i = 0; i < 16; ++i) {
    int c = cs * 16 + i;
    float v = xv[i] * inv * w[c];
    xn[c * NPIX + p] = v;
    hv.h[i] = (f16)v;
  }
  // 16 consecutive f16 per thread -> two 16B stores (was 16 scalar 2B stores)
  *(f16x8*)(xnT + (size_t)p * CIN + cs * 16) = hv.v[0];
  *(f16x8*)(xnT + (size_t)p * CIN + cs * 16 + 8) = hv.v[1];
}

// ---------------- K2: QKV GEMM, wave tile 32x64 ----------------
// grid (32, 24). Sections 0/1 (q,k) compute D=[p][o] (swapped operands) so the
// [head][p][d] store is 16-lane-contiguous; section 2 (v) computes D=[o][p].
// Section 0 (q) is pre-scaled by 0.125*log2(e) so attn uses exp2(s) directly.
__global__ __launch_bounds__(256) void k_qkv(const f16* __restrict__ wqkv,
                                             const f16* __restrict__ xnT,
                                             f16* __restrict__ qT,
                                             f16* __restrict__ kT,
                                             f16* __restrict__ vv) {
  const int lane = threadIdx.x & 63, wave = threadIdx.x >> 6;
  const int l15 = lane & 15, quad = lane >> 4;
  const int obase = blockIdx.y * 64 + (wave >> 1) * 32;
  const int pbase = blockIdx.x * 128 + (wave & 1) * 64;
  const int sect = blockIdx.y >> 3;  // 0=q, 1=k, 2=v
  f32x4 acc[8];
#pragma unroll
  for (int i = 0; i < 8; ++i) acc[i] = (f32x4){0.f, 0.f, 0.f, 0.f};
#pragma unroll
  for (int kc = 0; kc < CIN / 32; ++kc) {
    f16x8 af[2], bfr[4];
#pragma unroll
    for (int oc = 0; oc < 2; ++oc)
      af[oc] = *(const f16x8*)(wqkv + (size_t)(obase + oc * 16 + l15) * CIN + kc * 32 + quad * 8);
#pragma unroll
    for (int pc = 0; pc < 4; ++pc)
      bfr[pc] = *(const f16x8*)(xnT + (size_t)(pbase + pc * 16 + l15) * CIN + kc * 32 + quad * 8);
    if (sect < 2) {
#pragma unroll
      for (int pc = 0; pc < 4; ++pc)
#pragma unroll
        for (int oc = 0; oc < 2; ++oc)
          acc[pc * 2 + oc] = mfma_f16(bfr[pc], af[oc], acc[pc * 2 + oc]);
    } else {
#pragma unroll
      for (int oc = 0; oc < 2; ++oc)
#pragma unroll
        for (int pc = 0; pc < 4; ++pc)
          acc[oc * 4 + pc] = mfma_f16(af[oc], bfr[pc], acc[oc * 4 + pc]);
    }
  }
  if (sect < 2) {
    f16* dst = (sect == 0) ? qT : kT;
    const float sc = (sect == 0) ? 0.18033688f : 1.0f;  // 0.125*log2(e)
    const int head = blockIdx.y & 7;
    const int dd = (wave >> 1) * 32;
#pragma unroll
    for (int pc = 0; pc < 4; ++pc)
#pragma unroll
      for (int oc = 0; oc < 2; ++oc)
#pragma unroll
        for (int r = 0; r < 4; ++r) {
          int p = pbase + pc * 16 + quad * 4 + r;
          dst[((size_t)(head << 12) + p) * DH + dd + oc * 16 + l15] =
              (f16)(acc[pc * 2 + oc][r] * sc);
        }
  } else {
#pragma unroll
    for (int oc = 0; oc < 2; ++oc)
#pragma unroll
      for (int r = 0; r < 4; ++r) {
        int o = obase + oc * 16 + quad * 4 + r - 2 * INNER;
#pragma unroll
        for (int pc = 0; pc < 4; ++pc)
          vv[(size_t)o * NPIX + pbase + pc * 16 + l15] = (f16)acc[oc * 4 + pc][r];
      }
  }
}

// ---------------- K3: flash attention ----------------
// grid 256 x 512 threads. Block = (head = bid&7, 128 queries); 8 waves all
// process the SAME 128 q, wave w owns keys [w*512,(w+1)*512).
// head = bid&7 -> round-robin XCD assignment puts one head per XCD, so the
// head's 1 MB K/V is L2-resident per XCD.
// Per 32-key iteration per wave: 32 S-MFMAs + 32 PV-MFMAs on 8 KB of K/V
// loads (2x the bytes/MFMA reuse of the 64q version -> half the VMEM-bound
// time). lsum via VALU + 2x shfl_xor (quad reduce), saving 24 VGPR.
// Merge of the 8 key-split partials: two f32 passes through 138 KB LDS.
__global__ __launch_bounds__(512) void k_attn(const f16* __restrict__ qT,
                                              const f16* __restrict__ kT,
                                              const f16* __restrict__ vv,
                                              f16* __restrict__ Ows) {
  const int head = blockIdx.x & 7;
  const int qb = (blockIdx.x >> 3) * 128;
  const int tid = threadIdx.x;
  const int wave = tid >> 6, lane = tid & 63;
  const int l15 = lane & 15, quad = lane >> 4;

  extern __shared__ float smem[];
  float (*Om)[4][64][17] = reinterpret_cast<float (*)[4][64][17]>(smem);        // [8]
  float (*Ll)[4][16]     = reinterpret_cast<float (*)[4][16]>(smem + 8 * 4 * 64 * 17);

  // Q B-frags: B[k=d][n=q] from qT[head][q][d]
  f16x8 qf[8][2];
#pragma unroll
  for (int qt = 0; qt < 8; ++qt)
#pragma unroll
    for (int kc = 0; kc < 2; ++kc)
      qf[qt][kc] = *(const f16x8*)(qT + ((size_t)(head << 12) + qb + qt * 16 + l15) * DH + kc * 32 + quad * 8);

  f32x4 o[8][4];
  float ol[8];
#pragma unroll
  for (int qt = 0; qt < 8; ++qt) {
#pragma unroll
    for (int c = 0; c < 4; ++c) o[qt][c] = (f32x4){0.f, 0.f, 0.f, 0.f};
    ol[qt] = 0.f;
  }

  const f16* kbase = kT + (size_t)(head << 12) * DH;
  const f16* vbase = vv + (size_t)(head * DH) * NPIX;
  const int kb0 = wave * (NPIX / 8);
  const int srcA = ((quad & 1) << 5) + l15;  // P^T permute source lanes
  const int srcB = srcA + 16;
  const bool hiQuad = quad >= 2;             // nc half select

  for (int it = 0; it < 16; ++it) {
    const int kb = kb0 + it * 32;
    // K for this tile (issued first; S-MFMA consumes after V issue + addr calc)
    f16x8 kf[2][2];
#pragma unroll
    for (int nc = 0; nc < 2; ++nc)
#pragma unroll
      for (int kc = 0; kc < 2; ++kc)
        kf[nc][kc] = *(const f16x8*)(kbase + (size_t)(kb + nc * 16 + l15) * DH + kc * 32 + quad * 8);
    // V for this tile (consumed after first softmax)
    f16x8 vf[4];
#pragma unroll
    for (int c = 0; c < 4; ++c)
      vf[c] = *(const f16x8*)(vbase + (size_t)(c * 16 + l15) * NPIX + kb + quad * 8);

#pragma unroll
    for (int qt = 0; qt < 8; ++qt) {
      // S^T[key][q] = K @ Q'^T (q pre-scaled; C-layout row=key, col=q)
      f32x4 s0 = mfma_f16(kf[0][0], qf[qt][0], (f32x4){0.f, 0.f, 0.f, 0.f});
      s0 = mfma_f16(kf[0][1], qf[qt][1], s0);
      f32x4 s1 = mfma_f16(kf[1][0], qf[qt][0], (f32x4){0.f, 0.f, 0.f, 0.f});
      s1 = mfma_f16(kf[1][1], qf[qt][1], s1);
      // p = exp2(s'), no max subtraction (|s'| << 1)
      float p0[4], p1[4];
#pragma unroll
      for (int r = 0; r < 4; ++r) {
        p0[r] = __builtin_amdgcn_exp2f(s0[r]);
        p1[r] = __builtin_amdgcn_exp2f(s1[r]);
      }
      // lsum for q=l15: per-lane partial over this quad's 8 keys, then
      // quad-reduce via lane^16, lane^32.
      float ps = ((p0[0] + p0[1]) + (p0[2] + p0[3])) +
                 ((p1[0] + p1[1]) + (p1[2] + p1[3]));
      ps += __shfl_xor(ps, 16);
      ps += __shfl_xor(ps, 32);
      ol[qt] += ps;
      // P^T C-layout -> B-frag: pack (r,r+1) pairs, 4 whole-dword shuffles.
      unsigned A0 = pk2(p0[0], p0[1]), B0 = pk2(p0[2], p0[3]);
      unsigned A1 = pk2(p1[0], p1[1]), B1 = pk2(p1[2], p1[3]);
      unsigned As = hiQuad ? A1 : A0;
      unsigned Bs = hiQuad ? B1 : B0;
      union { f16x8 v; unsigned u[4]; } pf;
      pf.u[0] = (unsigned)__shfl((int)As, srcA);
      pf.u[1] = (unsigned)__shfl((int)Bs, srcA);
      pf.u[2] = (unsigned)__shfl((int)As, srcB);
      pf.u[3] = (unsigned)__shfl((int)Bs, srcB);
      // O^T[d][q] += V^T @ P^T
#pragma unroll
      for (int c = 0; c < 4; ++c) o[qt][c] = mfma_f16(vf[c], pf.v, o[qt][c]);
    }
  }

  // Merge 8 key-split partials, two passes (4 q-tiles each) through LDS.
#pragma unroll
  for (int pass = 0; pass < 2; ++pass) {
    if (pass) __syncthreads();  // previous merge reads done before overwrite
#pragma unroll
    for (int qt2 = 0; qt2 < 4; ++qt2) {
      const int qt = pass * 4 + qt2;
      if (quad == 0) Ll[wave][qt2][l15] = ol[qt];
#pragma unroll
      for (int c = 0; c < 4; ++c)
#pragma unroll
        for (int r = 0; r < 4; ++r)
          Om[wave][qt2][c * 16 + quad * 4 + r][l15] = o[qt][c][r];
    }
    __syncthreads();
    // merge: wave -> (qt2 = wave>>1, q-half = wave&1), lanes over d
    const int d = tid & 63;
    const int mqt = wave >> 1, qh = (wave & 1) * 8;
#pragma unroll
    for (int j = 0; j < 8; ++j) {
      const int q = qh + j;
      float O = 0.f, L = 0.f;
#pragma unroll
      for (int w = 0; w < 8; ++w) {
        O += Om[w][mqt][d][q];
        L += Ll[w][mqt][q];
      }
      Ows[((size_t)(head << 12) + qb + (pass * 4 + mqt) * 16 + q) * DH + d] =
          (f16)(O / L);
    }
  }
}

// ---------------- K4: out projection + bias + residual ----------------
// grid (64, 8), wave tile 16x32
__global__ __launch_bounds__(256) void k_oproj(const f16* __restrict__ wout,
                                               const f16* __restrict__ Ows,
                                               const float* __restrict__ bout,
                                               const float* __restrict__ xn,
                                               float* __restrict__ out) {
  const int lane = threadIdx.x & 63, wave = threadIdx.x >> 6;
  const int l15 = lane & 15, quad = lane >> 4;
  const int mbase = blockIdx.y * 32 + (wave >> 1) * 16;
  const int pbase = blockIdx.x * 64 + (wave & 1) * 32;
  f32x4 acc[2];
  acc[0] = (f32x4){0.f, 0.f, 0.f, 0.f};
  acc[1] = (f32x4){0.f, 0.f, 0.f, 0.f};
#pragma unroll
  for (int kc = 0; kc < INNER / 32; ++kc) {
    f16x8 af = *(const f16x8*)(wout + (size_t)(mbase + l15) * INNER + kc * 32 + quad * 8);
    int i0 = kc * 32 + quad * 8;
    int head = i0 >> 6, d0 = i0 & 63;
#pragma unroll
    for (int pc = 0; pc < 2; ++pc) {
      f16x8 bfr = *(const f16x8*)(Ows + ((size_t)(head << 12) + pbase + pc * 16 + l15) * DH + d0);
      acc[pc] = mfma_f16(af, bfr, acc[pc]);
    }
  }
#pragma unroll
  for (int pc = 0; pc < 2; ++pc)
#pragma unroll
    for (int r = 0; r < 4; ++r) {
      int c = mbase + quad * 4 + r, p = pbase + pc * 16 + l15;
      out[c * NPIX + p] = acc[pc][r] + bout[c] + xn[c * NPIX + p];
    }
}

extern "C" void kernel_launch(void* const* d_in, const int* in_sizes, int n_in,
                              void* d_out, int out_size, void* d_ws, size_t ws_size,
                              hipStream_t stream) {
  (void)in_sizes; (void)n_in; (void)out_size; (void)ws_size;
  const float* x      = (const float*)d_in[0];
  const float* norm_w = (const float*)d_in[1];
  const float* w_qkv  = (const float*)d_in[2];
  const float* w_out  = (const float*)d_in[3];
  const float* b_out  = (const float*)d_in[4];
  float* out = (float*)d_out;

  char* ws = (char*)d_ws;
  float* xn    = (float*)(ws);                 // 4 MB
  f16* xnT     = (f16*)(ws + (4u << 20));      // 2 MB
  f16* qT      = (f16*)(ws + (6u << 20));      // 4 MB  [head][p][d], pre-scaled
  f16* kT      = (f16*)(ws + (10u << 20));     // 4 MB  [head][p][d]
  f16* vv      = (f16*)(ws + (14u << 20));     // 4 MB  [head*64+d][p]
  f16* Ows     = (f16*)(ws + (18u << 20));     // 4 MB  [head][p][d]
  f16* wqkv_h  = (f16*)(ws + (22u << 20));     // 0.75 MB
  f16* wout_h  = (f16*)(ws + (23u << 20));     // 0.25 MB

  hipLaunchKernelGGL(k_cvt, dim3((3 * INNER * CIN + 255) / 256), dim3(256), 0, stream,
                     w_qkv, wqkv_h, 3 * INNER * CIN);
  hipLaunchKernelGGL(k_cvt, dim3((CIN * INNER + 255) / 256), dim3(256), 0, stream,
                     w_out, wout_h, CIN * INNER);
  hipLaunchKernelGGL(k_rmsnorm, dim3(NPIX / 16), dim3(256), 0, stream, x, norm_w, xn, xnT);
  hipLaunchKernelGGL(k_qkv, dim3(NPIX / 128, 1536 / 64), dim3(256), 0, stream,
                     wqkv_h, xnT, qT, kT, vv);
  // dynamic LDS: 8*4*64*17 + 8*4*16 floats = 141312 B
  hipLaunchKernelGGL(k_attn, dim3(256), dim3(512), 141312, stream,
                     qT, kT, vv, Ows);
  hipLaunchKernelGGL(k_oproj, dim3(NPIX / 64, CIN / 32), dim3(256), 0, stream,
                     wout_h, Ows, b_out, xn, out);
}

// Round 3
// 169.135 us; speedup vs baseline: 1.3144x; 1.0182x over previous
//
#include <hip/hip_runtime.h>

// FullAttention fused block on gfx950. fp32 harness I/O, fp16 MFMA internally.
//
// Pipeline:
//   k_cvt2    : w_qkv + w_out fp32 -> f16 (single launch, contiguous dst)
//   k_rmsnorm : x[C][N] -> xn[C][N] fp32 (residual) + xnT[N][C] f16
//   k_qkv     : GEMM 1536x256x4096 -> qT/kT [head][p][d] f16 (q pre-scaled by
//               0.125*log2e), vv [d'][p] f16
//   k_attn    : flash attention. r1/r2 A/B established: K/V bytes/CU pin the
//               kernel when > ~13 B/cyc/CU (VMEM service ceiling); at 128 q
//               per wave (268 MB total) we are at 5.7 B/cyc -> latency-bound
//               at 2 waves/SIMD (256-reg budget is exactly full).
//               This round: per-wave ILP. 2-state software pipeline over
//               q-tiles (S(qt+1) MFMAs issued before softmax(qt), T15),
//               lsum quad-reduce deferred out of the key loop (removes 2
//               LDS-pipe ops from the per-qt chain), setprio around MFMA
//               clusters (T5; 2 unsynchronized waves/SIMD = role diversity).
//   k_oproj   : GEMM 256x512x4096 + bias + residual -> fp32 out
//
// MFMA 16x16x32 layouts (HW-verified per guide):
//   A-frag: lane holds A[m=lane&15][k=quad*8+j], j=0..7
//   B-frag: lane holds B[k=quad*8+j][n=lane&15]
//   C/D   : lane holds D[row=quad*4+reg][col=lane&15], reg=0..3

#define NPIX 4096
#define CIN 256
#define INNER 512
#define NHEAD 8
#define DH 64

typedef _Float16 f16;
typedef __attribute__((ext_vector_type(8))) _Float16 f16x8;
typedef __attribute__((ext_vector_type(4))) float f32x4;

static __device__ __forceinline__ f32x4 mfma_f16(f16x8 a, f16x8 b, f32x4 c) {
  return __builtin_amdgcn_mfma_f32_16x16x32_f16(a, b, c, 0, 0, 0);
}

static __device__ __forceinline__ unsigned pk2(float lo, float hi) {
  return __builtin_bit_cast(unsigned, __builtin_amdgcn_cvt_pkrtz(lo, hi));
}

// ---------------- K0: fp32 -> f16, two sources, contiguous dst ----------------
__global__ __launch_bounds__(256) void k_cvt2(const float* __restrict__ a1, int n1,
                                              const float* __restrict__ a2, int n2,
                                              f16* __restrict__ b) {
  int i = blockIdx.x * 256 + threadIdx.x;
  if (i < n1) b[i] = (f16)a1[i];
  else if (i < n1 + n2) b[i] = (f16)a2[i - n1];
}

// ---------------- K1: RMSNorm (256 blocks, 16 pixels each) ----------------
__global__ __launch_bounds__(256) void k_rmsnorm(const float* __restrict__ x,
                                                 const float* __restrict__ w,
                                                 float* __restrict__ xn,
                                                 f16* __restrict__ xnT) {
  const int pi = threadIdx.x & 15, cs = threadIdx.x >> 4;
  const int p = blockIdx.x * 16 + pi;
  __shared__ float red[16][16];
  float xv[16];
  float ss = 0.f;
#pragma unroll
  for (int i = 0; i < 16; ++i) {
    xv[i] = x[(cs * 16 + i) * NPIX + p];
    ss += xv[i] * xv[i];
  }
  red[cs][pi] = ss;
  __syncthreads();
  float tot = 0.f;
#pragma unroll
  for (int s = 0; s < 16; ++s) tot += red[s][pi];
  float inv = 16.0f / fmaxf(sqrtf(tot), 1e-12f);  // sqrt(256)=16
  union { f16x8 v[2]; f16 h[16]; } hv;
#pragma unroll
  for (int i = 0; i < 16; ++i) {
    int c = cs * 16 + i;
    float v = xv[i] * inv * w[c];
    xn[c * NPIX + p] = v;
    hv.h[i] = (f16)v;
  }
  // 16 consecutive f16 per thread -> two 16B stores
  *(f16x8*)(xnT + (size_t)p * CIN + cs * 16) = hv.v[0];
  *(f16x8*)(xnT + (size_t)p * CIN + cs * 16 + 8) = hv.v[1];
}

// ---------------- K2: QKV GEMM, wave tile 32x64 ----------------
// grid (32, 24). Sections 0/1 (q,k) compute D=[p][o] (swapped operands) so the
// [head][p][d] store is 16-lane-contiguous; section 2 (v) computes D=[o][p].
// Section 0 (q) is pre-scaled by 0.125*log2(e) so attn uses exp2(s) directly.
__global__ __launch_bounds__(256) void k_qkv(const f16* __restrict__ wqkv,
                                             const f16* __restrict__ xnT,
                                             f16* __restrict__ qT,
                                             f16* __restrict__ kT,
                                             f16* __restrict__ vv) {
  const int lane = threadIdx.x & 63, wave = threadIdx.x >> 6;
  const int l15 = lane & 15, quad = lane >> 4;
  const int obase = blockIdx.y * 64 + (wave >> 1) * 32;
  const int pbase = blockIdx.x * 128 + (wave & 1) * 64;
  const int sect = blockIdx.y >> 3;  // 0=q, 1=k, 2=v
  f32x4 acc[8];
#pragma unroll
  for (int i = 0; i < 8; ++i) acc[i] = (f32x4){0.f, 0.f, 0.f, 0.f};
#pragma unroll
  for (int kc = 0; kc < CIN / 32; ++kc) {
    f16x8 af[2], bfr[4];
#pragma unroll
    for (int oc = 0; oc < 2; ++oc)
      af[oc] = *(const f16x8*)(wqkv + (size_t)(obase + oc * 16 + l15) * CIN + kc * 32 + quad * 8);
#pragma unroll
    for (int pc = 0; pc < 4; ++pc)
      bfr[pc] = *(const f16x8*)(xnT + (size_t)(pbase + pc * 16 + l15) * CIN + kc * 32 + quad * 8);
    if (sect < 2) {
#pragma unroll
      for (int pc = 0; pc < 4; ++pc)
#pragma unroll
        for (int oc = 0; oc < 2; ++oc)
          acc[pc * 2 + oc] = mfma_f16(bfr[pc], af[oc], acc[pc * 2 + oc]);
    } else {
#pragma unroll
      for (int oc = 0; oc < 2; ++oc)
#pragma unroll
        for (int pc = 0; pc < 4; ++pc)
          acc[oc * 4 + pc] = mfma_f16(af[oc], bfr[pc], acc[oc * 4 + pc]);
    }
  }
  if (sect < 2) {
    f16* dst = (sect == 0) ? qT : kT;
    const float sc = (sect == 0) ? 0.18033688f : 1.0f;  // 0.125*log2(e)
    const int head = blockIdx.y & 7;
    const int dd = (wave >> 1) * 32;
#pragma unroll
    for (int pc = 0; pc < 4; ++pc)
#pragma unroll
      for (int oc = 0; oc < 2; ++oc)
#pragma unroll
        for (int r = 0; r < 4; ++r) {
          int p = pbase + pc * 16 + quad * 4 + r;
          dst[((size_t)(head << 12) + p) * DH + dd + oc * 16 + l15] =
              (f16)(acc[pc * 2 + oc][r] * sc);
        }
  } else {
#pragma unroll
    for (int oc = 0; oc < 2; ++oc)
#pragma unroll
      for (int r = 0; r < 4; ++r) {
        int o = obase + oc * 16 + quad * 4 + r - 2 * INNER;
#pragma unroll
        for (int pc = 0; pc < 4; ++pc)
          vv[(size_t)o * NPIX + pbase + pc * 16 + l15] = (f16)acc[oc * 4 + pc][r];
      }
  }
}

// ---------------- K3: flash attention ----------------
// grid 256 x 512 threads. Block = (head = bid&7, 128 queries); 8 waves all
// process the SAME 128 q, wave w owns keys [w*512,(w+1)*512).
// head = bid&7 -> one head per XCD, K/V L2-resident (FETCH 9.3 MB, r2-verified).
// Inner loop: 2-state qt pipeline -- S(qt+1) issued before softmax(qt) so the
// wave only ever waits on bpermute latency; lsum reduced after the key loop.
__global__ __launch_bounds__(512, 2) void k_attn(const f16* __restrict__ qT,
                                                 const f16* __restrict__ kT,
                                                 const f16* __restrict__ vv,
                                                 f16* __restrict__ Ows) {
  const int head = blockIdx.x & 7;
  const int qb = (blockIdx.x >> 3) * 128;
  const int tid = threadIdx.x;
  const int wave = tid >> 6, lane = tid & 63;
  const int l15 = lane & 15, quad = lane >> 4;

  extern __shared__ float smem[];
  float (*Om)[4][64][17] = reinterpret_cast<float (*)[4][64][17]>(smem);  // [8]
  float (*Ll)[4][16]     = reinterpret_cast<float (*)[4][16]>(smem + 8 * 4 * 64 * 17);

  // Q B-frags: B[k=d][n=q] from qT[head][q][d]
  f16x8 qf[8][2];
#pragma unroll
  for (int qt = 0; qt < 8; ++qt)
#pragma unroll
    for (int kc = 0; kc < 2; ++kc)
      qf[qt][kc] = *(const f16x8*)(qT + ((size_t)(head << 12) + qb + qt * 16 + l15) * DH + kc * 32 + quad * 8);

  f32x4 o[8][4];
  float ol[8];
#pragma unroll
  for (int qt = 0; qt < 8; ++qt) {
#pragma unroll
    for (int c = 0; c < 4; ++c) o[qt][c] = (f32x4){0.f, 0.f, 0.f, 0.f};
    ol[qt] = 0.f;
  }

  const f16* kbase = kT + (size_t)(head << 12) * DH;
  const f16* vbase = vv + (size_t)(head * DH) * NPIX;
  const int kb0 = wave * (NPIX / 8);
  const int srcA4 = (((quad & 1) << 5) + l15) * 4;  // P^T permute byte indices
  const int srcB4 = srcA4 + 64;
  const bool hiQuad = quad >= 2;                    // nc half select

  for (int it = 0; it < 16; ++it) {
    const int kb = kb0 + it * 32;
    f16x8 kf[2][2];
#pragma unroll
    for (int nc = 0; nc < 2; ++nc)
#pragma unroll
      for (int kc = 0; kc < 2; ++kc)
        kf[nc][kc] = *(const f16x8*)(kbase + (size_t)(kb + nc * 16 + l15) * DH + kc * 32 + quad * 8);
    f16x8 vf[4];
#pragma unroll
    for (int c = 0; c < 4; ++c)
      vf[c] = *(const f16x8*)(vbase + (size_t)(c * 16 + l15) * NPIX + kb + quad * 8);

    // S^T[key][q] = K @ Q'^T (q pre-scaled; C-layout row=key, col=q)
#define S_QT(QT, S)                                                       \
  do {                                                                    \
    S[0] = mfma_f16(kf[0][0], qf[QT][0], (f32x4){0.f, 0.f, 0.f, 0.f});    \
    S[0] = mfma_f16(kf[0][1], qf[QT][1], S[0]);                           \
    S[1] = mfma_f16(kf[1][0], qf[QT][0], (f32x4){0.f, 0.f, 0.f, 0.f});    \
    S[1] = mfma_f16(kf[1][1], qf[QT][1], S[1]);                           \
  } while (0)

    f32x4 sc[2], sn[2];
    __builtin_amdgcn_s_setprio(1);
    S_QT(0, sc);
    __builtin_amdgcn_s_setprio(0);
#pragma unroll
    for (int qt = 0; qt < 8; ++qt) {
      if (qt < 7) {
        // next tile's S-MFMAs fill the matrix pipe while softmax(qt) runs
        __builtin_amdgcn_s_setprio(1);
        S_QT(qt + 1, sn);
        __builtin_amdgcn_s_setprio(0);
      }
      // p = exp2(s'), no max subtraction (|s'| << 1)
      float p0[4], p1[4];
#pragma unroll
      for (int r = 0; r < 4; ++r) {
        p0[r] = __builtin_amdgcn_exp2f(sc[0][r]);
        p1[r] = __builtin_amdgcn_exp2f(sc[1][r]);
      }
      // per-lane lsum partial (lane's 8 keys for q=l15); quad-reduce deferred
      ol[qt] += ((p0[0] + p0[1]) + (p0[2] + p0[3])) +
                ((p1[0] + p1[1]) + (p1[2] + p1[3]));
      // P^T C-layout -> B-frag: pack (r,r+1) pairs, 4 whole-dword bpermutes
      unsigned A0 = pk2(p0[0], p0[1]), B0 = pk2(p0[2], p0[3]);
      unsigned A1 = pk2(p1[0], p1[1]), B1 = pk2(p1[2], p1[3]);
      unsigned As = hiQuad ? A1 : A0;
      unsigned Bs = hiQuad ? B1 : B0;
      union { f16x8 v; unsigned u[4]; } pf;
      pf.u[0] = (unsigned)__builtin_amdgcn_ds_bpermute(srcA4, (int)As);
      pf.u[1] = (unsigned)__builtin_amdgcn_ds_bpermute(srcA4, (int)Bs);
      pf.u[2] = (unsigned)__builtin_amdgcn_ds_bpermute(srcB4, (int)As);
      pf.u[3] = (unsigned)__builtin_amdgcn_ds_bpermute(srcB4, (int)Bs);
      // O^T[d][q] += V^T @ P^T
      __builtin_amdgcn_s_setprio(1);
#pragma unroll
      for (int c = 0; c < 4; ++c) o[qt][c] = mfma_f16(vf[c], pf.v, o[qt][c]);
      __builtin_amdgcn_s_setprio(0);
      if (qt < 7) { sc[0] = sn[0]; sc[1] = sn[1]; }
    }
#undef S_QT
  }

  // deferred lsum quad-reduce (once, not per key-tile)
#pragma unroll
  for (int qt = 0; qt < 8; ++qt) {
    ol[qt] += __shfl_xor(ol[qt], 16);
    ol[qt] += __shfl_xor(ol[qt], 32);
  }

  // Merge 8 key-split partials, two passes (4 q-tiles each) through LDS.
#pragma unroll
  for (int pass = 0; pass < 2; ++pass) {
    if (pass) __syncthreads();  // previous merge reads done before overwrite
#pragma unroll
    for (int qt2 = 0; qt2 < 4; ++qt2) {
      const int qt = pass * 4 + qt2;
      if (quad == 0) Ll[wave][qt2][l15] = ol[qt];
#pragma unroll
      for (int c = 0; c < 4; ++c)
#pragma unroll
        for (int r = 0; r < 4; ++r)
          Om[wave][qt2][c * 16 + quad * 4 + r][l15] = o[qt][c][r];
    }
    __syncthreads();
    // merge: wave -> (qt2 = wave>>1, q-half = wave&1), lanes over d
    const int d = tid & 63;
    const int mqt = wave >> 1, qh = (wave & 1) * 8;
#pragma unroll
    for (int j = 0; j < 8; ++j) {
      const int q = qh + j;
      float O = 0.f, L = 0.f;
#pragma unroll
      for (int w = 0; w < 8; ++w) {
        O += Om[w][mqt][d][q];
        L += Ll[w][mqt][q];
      }
      Ows[((size_t)(head << 12) + qb + (pass * 4 + mqt) * 16 + q) * DH + d] =
          (f16)(O / L);
    }
  }
}

// ---------------- K4: out projection + bias + residual ----------------
// grid (64, 8), wave tile 16x32
__global__ __launch_bounds__(256) void k_oproj(const f16* __restrict__ wout,
                                               const f16* __restrict__ Ows,
                                               const float* __restrict__ bout,
                                               const float* __restrict__ xn,
                                               float* __restrict__ out) {
  const int lane = threadIdx.x & 63, wave = threadIdx.x >> 6;
  const int l15 = lane & 15, quad = lane >> 4;
  const int mbase = blockIdx.y * 32 + (wave >> 1) * 16;
  const int pbase = blockIdx.x * 64 + (wave & 1) * 32;
  f32x4 acc[2];
  acc[0] = (f32x4){0.f, 0.f, 0.f, 0.f};
  acc[1] = (f32x4){0.f, 0.f, 0.f, 0.f};
#pragma unroll
  for (int kc = 0; kc < INNER / 32; ++kc) {
    f16x8 af = *(const f16x8*)(wout + (size_t)(mbase + l15) * INNER + kc * 32 + quad * 8);
    int i0 = kc * 32 + quad * 8;
    int head = i0 >> 6, d0 = i0 & 63;
#pragma unroll
    for (int pc = 0; pc < 2; ++pc) {
      f16x8 bfr = *(const f16x8*)(Ows + ((size_t)(head << 12) + pbase + pc * 16 + l15) * DH + d0);
      acc[pc] = mfma_f16(af, bfr, acc[pc]);
    }
  }
#pragma unroll
  for (int pc = 0; pc < 2; ++pc)
#pragma unroll
    for (int r = 0; r < 4; ++r) {
      int c = mbase + quad * 4 + r, p = pbase + pc * 16 + l15;
      out[c * NPIX + p] = acc[pc][r] + bout[c] + xn[c * NPIX + p];
    }
}

extern "C" void kernel_launch(void* const* d_in, const int* in_sizes, int n_in,
                              void* d_out, int out_size, void* d_ws, size_t ws_size,
                              hipStream_t stream) {
  (void)in_sizes; (void)n_in; (void)out_size; (void)ws_size;
  const float* x      = (const float*)d_in[0];
  const float* norm_w = (const float*)d_in[1];
  const float* w_qkv  = (const float*)d_in[2];
  const float* w_out  = (const float*)d_in[3];
  const float* b_out  = (const float*)d_in[4];
  float* out = (float*)d_out;

  char* ws = (char*)d_ws;
  float* xn    = (float*)(ws);                 // 4 MB
  f16* xnT     = (f16*)(ws + (4u << 20));      // 2 MB
  f16* qT      = (f16*)(ws + (6u << 20));      // 4 MB  [head][p][d], pre-scaled
  f16* kT      = (f16*)(ws + (10u << 20));     // 4 MB  [head][p][d]
  f16* vv      = (f16*)(ws + (14u << 20));     // 4 MB  [head*64+d][p]
  f16* Ows     = (f16*)(ws + (18u << 20));     // 4 MB  [head][p][d]
  f16* wqkv_h  = (f16*)(ws + (22u << 20));             // 0.75 MB
  f16* wout_h  = (f16*)(ws + (22u << 20) + 786432);    // 0.25 MB, contiguous

  const int n1 = 3 * INNER * CIN, n2 = CIN * INNER;
  hipLaunchKernelGGL(k_cvt2, dim3((n1 + n2 + 255) / 256), dim3(256), 0, stream,
                     w_qkv, n1, w_out, n2, wqkv_h);
  hipLaunchKernelGGL(k_rmsnorm, dim3(NPIX / 16), dim3(256), 0, stream, x, norm_w, xn, xnT);
  hipLaunchKernelGGL(k_qkv, dim3(NPIX / 128, 1536 / 64), dim3(256), 0, stream,
                     wqkv_h, xnT, qT, kT, vv);
  // dynamic LDS: 8*4*64*17 + 8*4*16 floats = 141312 B
  hipLaunchKernelGGL(k_attn, dim3(256), dim3(512), 141312, stream,
                     qT, kT, vv, Ows);
  hipLaunchKernelGGL(k_oproj, dim3(NPIX / 64, CIN / 32), dim3(256), 0, stream,
                     wout_h, Ows, b_out, xn, out);
}

// Round 4
// 154.833 us; speedup vs baseline: 1.4358x; 1.0924x over previous
//
#include <hip/hip_runtime.h>

// FullAttention fused block on gfx950. fp32 harness I/O, fp16 MFMA internally.
//
// Pipeline:
//   k_cvt2    : w_qkv + w_out fp32 -> f16 (single launch)
//   k_rmsnorm : x[C][N] -> xn[C][N] fp32 (residual) + xnT[N][C] f16
//   k_qkv     : GEMM 1536x256x4096 -> qT/kT [head][p][d] f16 (q pre-scaled by
//               0.125*log2e), vv [d'][p] f16
//   k_attn    : flash attention, restructured (r0-r3 established: per-wave
//               K/V-in-reg forces 2 waves/SIMD (acc AGPRs) OR busts the
//               ~13 B/cyc/CU VMEM ceiling). Now: K/V staged in LDS per block,
//               4 waves q-split (32 q each) consume the same staged keys ->
//               32 AGPR acc/wave, ~116 regs total -> 4 waves/SIMD at 4
//               blocks/CU. 4-way key-split across blocks (same XCD), f32
//               partials merged by k_merge. Staging via global_load_lds w=16,
//               pre-swizzled source + XOR-swizzled ds_read (conflict-free).
//   k_merge   : sum 4 key-split partials, divide by lsum -> Ows f16
//   k_oproj   : GEMM 256x512x4096 + bias + residual -> fp32 out
//
// MFMA 16x16x32 layouts (HW-verified per guide):
//   A-frag: lane holds A[m=lane&15][k=quad*8+j], j=0..7
//   B-frag: lane holds B[k=quad*8+j][n=lane&15]
//   C/D   : lane holds D[row=quad*4+reg][col=lane&15], reg=0..3

#define NPIX 4096
#define CIN 256
#define INNER 512
#define NHEAD 8
#define DH 64

typedef _Float16 f16;
typedef __attribute__((ext_vector_type(8))) _Float16 f16x8;
typedef __attribute__((ext_vector_type(4))) float f32x4;

static __device__ __forceinline__ f32x4 mfma_f16(f16x8 a, f16x8 b, f32x4 c) {
  return __builtin_amdgcn_mfma_f32_16x16x32_f16(a, b, c, 0, 0, 0);
}

static __device__ __forceinline__ unsigned pk2(float lo, float hi) {
  return __builtin_bit_cast(unsigned, __builtin_amdgcn_cvt_pkrtz(lo, hi));
}

// async global->LDS, 16 B per lane; LDS dest = wave-uniform base + lane*16
static __device__ __forceinline__ void gload_lds16(const void* g, void* l) {
  __builtin_amdgcn_global_load_lds(
      (const __attribute__((address_space(1))) unsigned*)g,
      (__attribute__((address_space(3))) unsigned*)l, 16, 0, 0);
}

// ---------------- K0: fp32 -> f16, two sources, contiguous dst ----------------
__global__ __launch_bounds__(256) void k_cvt2(const float* __restrict__ a1, int n1,
                                              const float* __restrict__ a2, int n2,
                                              f16* __restrict__ b) {
  int i = blockIdx.x * 256 + threadIdx.x;
  if (i < n1) b[i] = (f16)a1[i];
  else if (i < n1 + n2) b[i] = (f16)a2[i - n1];
}

// ---------------- K1: RMSNorm (256 blocks, 16 pixels each) ----------------
__global__ __launch_bounds__(256) void k_rmsnorm(const float* __restrict__ x,
                                                 const float* __restrict__ w,
                                                 float* __restrict__ xn,
                                                 f16* __restrict__ xnT) {
  const int pi = threadIdx.x & 15, cs = threadIdx.x >> 4;
  const int p = blockIdx.x * 16 + pi;
  __shared__ float red[16][16];
  float xv[16];
  float ss = 0.f;
#pragma unroll
  for (int i = 0; i < 16; ++i) {
    xv[i] = x[(cs * 16 + i) * NPIX + p];
    ss += xv[i] * xv[i];
  }
  red[cs][pi] = ss;
  __syncthreads();
  float tot = 0.f;
#pragma unroll
  for (int s = 0; s < 16; ++s) tot += red[s][pi];
  float inv = 16.0f / fmaxf(sqrtf(tot), 1e-12f);  // sqrt(256)=16
  union { f16x8 v[2]; f16 h[16]; } hv;
#pragma unroll
  for (int i = 0; i < 16; ++i) {
    int c = cs * 16 + i;
    float v = xv[i] * inv * w[c];
    xn[c * NPIX + p] = v;
    hv.h[i] = (f16)v;
  }
  *(f16x8*)(xnT + (size_t)p * CIN + cs * 16) = hv.v[0];
  *(f16x8*)(xnT + (size_t)p * CIN + cs * 16 + 8) = hv.v[1];
}

// ---------------- K2: QKV GEMM, wave tile 32x64 ----------------
__global__ __launch_bounds__(256) void k_qkv(const f16* __restrict__ wqkv,
                                             const f16* __restrict__ xnT,
                                             f16* __restrict__ qT,
                                             f16* __restrict__ kT,
                                             f16* __restrict__ vv) {
  const int lane = threadIdx.x & 63, wave = threadIdx.x >> 6;
  const int l15 = lane & 15, quad = lane >> 4;
  const int obase = blockIdx.y * 64 + (wave >> 1) * 32;
  const int pbase = blockIdx.x * 128 + (wave & 1) * 64;
  const int sect = blockIdx.y >> 3;  // 0=q, 1=k, 2=v
  f32x4 acc[8];
#pragma unroll
  for (int i = 0; i < 8; ++i) acc[i] = (f32x4){0.f, 0.f, 0.f, 0.f};
#pragma unroll
  for (int kc = 0; kc < CIN / 32; ++kc) {
    f16x8 af[2], bfr[4];
#pragma unroll
    for (int oc = 0; oc < 2; ++oc)
      af[oc] = *(const f16x8*)(wqkv + (size_t)(obase + oc * 16 + l15) * CIN + kc * 32 + quad * 8);
#pragma unroll
    for (int pc = 0; pc < 4; ++pc)
      bfr[pc] = *(const f16x8*)(xnT + (size_t)(pbase + pc * 16 + l15) * CIN + kc * 32 + quad * 8);
    if (sect < 2) {
#pragma unroll
      for (int pc = 0; pc < 4; ++pc)
#pragma unroll
        for (int oc = 0; oc < 2; ++oc)
          acc[pc * 2 + oc] = mfma_f16(bfr[pc], af[oc], acc[pc * 2 + oc]);
    } else {
#pragma unroll
      for (int oc = 0; oc < 2; ++oc)
#pragma unroll
        for (int pc = 0; pc < 4; ++pc)
          acc[oc * 4 + pc] = mfma_f16(af[oc], bfr[pc], acc[oc * 4 + pc]);
    }
  }
  if (sect < 2) {
    f16* dst = (sect == 0) ? qT : kT;
    const float sc = (sect == 0) ? 0.18033688f : 1.0f;  // 0.125*log2(e)
    const int head = blockIdx.y & 7;
    const int dd = (wave >> 1) * 32;
#pragma unroll
    for (int pc = 0; pc < 4; ++pc)
#pragma unroll
      for (int oc = 0; oc < 2; ++oc)
#pragma unroll
        for (int r = 0; r < 4; ++r) {
          int p = pbase + pc * 16 + quad * 4 + r;
          dst[((size_t)(head << 12) + p) * DH + dd + oc * 16 + l15] =
              (f16)(acc[pc * 2 + oc][r] * sc);
        }
  } else {
#pragma unroll
    for (int oc = 0; oc < 2; ++oc)
#pragma unroll
      for (int r = 0; r < 4; ++r) {
        int o = obase + oc * 16 + quad * 4 + r - 2 * INNER;
#pragma unroll
        for (int pc = 0; pc < 4; ++pc)
          vv[(size_t)o * NPIX + pbase + pc * 16 + l15] = (f16)acc[oc * 4 + pc][r];
      }
  }
}

// ---------------- K3: flash attention (LDS-staged K/V, q-split waves) --------
// grid 1024 x 256 threads. bid -> head = bid&7 (one head per XCD), split =
// (bid>>3)&3 (key quarter, partner blocks on same XCD), qb = bid>>5 (0..31).
// Block: 4 waves x 32 q = 128 q, keys [split*1024, split*1024+1024) staged
// through LDS in 16 double-buffered 64-key chunks (K 8 KB + V 8 KB each).
// LDS swizzle: 16B-column index ^= (row&7) on the global SOURCE address
// (global_load_lds writes linearly) and on the ds_read address -> every
// frag read is 2 lanes/bank (free). One barrier per chunk; next chunk's
// loads issued before compute (latency hidden under ~2500 cyc of MFMA).
template <typename PT>
__global__ __launch_bounds__(256, 4) void k_attn(const f16* __restrict__ qT,
                                                 const f16* __restrict__ kT,
                                                 const f16* __restrict__ vv,
                                                 PT* __restrict__ Opart,
                                                 float* __restrict__ Lpart) {
  const int bid = blockIdx.x;
  const int head = bid & 7, split = (bid >> 3) & 3, qb = bid >> 5;
  const int tid = threadIdx.x;
  const int wave = tid >> 6, lane = tid & 63;
  const int l15 = lane & 15, quad = lane >> 4;
  const int keybase = split * 1024;

  __shared__ f16 KV[2][8192];  // per buf: [0,4096) = K chunk, [4096,8192) = V

  // Q B-frags: B[k=d][n=q] from qT[head][q][d]
  const int qrow = (head << 12) + qb * 128 + wave * 32;
  f16x8 qf[2][2];
#pragma unroll
  for (int qt = 0; qt < 2; ++qt)
#pragma unroll
    for (int kc = 0; kc < 2; ++kc)
      qf[qt][kc] = *(const f16x8*)(qT + (size_t)(qrow + qt * 16 + l15) * DH + kc * 32 + quad * 8);

  f32x4 o[2][4];
  float ol[2] = {0.f, 0.f};
#pragma unroll
  for (int qt = 0; qt < 2; ++qt)
#pragma unroll
    for (int c = 0; c < 4; ++c) o[qt][c] = (f32x4){0.f, 0.f, 0.f, 0.f};

  const int sKey8 = lane >> 3;  // staging: row sub-index within 1 KB region
  const int sCol = lane & 7;    // staging: 16B column
  const int rx = l15 & 7;       // read-side swizzle xor (row&7 == l15&7 here)
  const int srcA4 = (((quad & 1) << 5) + l15) * 4;  // P^T bpermute byte idx
  const int srcB4 = srcA4 + 64;
  const bool hiQuad = quad >= 2;

  // stage chunk ch (64 keys) into buffer b: 4 x global_load_lds per wave.
  // LDS linear byte L = R + lane*16; logical row = L>>7, col16 = (L>>4)&7;
  // source column pre-swizzled: gcol16 = col16 ^ (row&7).
  auto stage = [&](int ch, int b) {
    const int R0 = wave * 4096;
#pragma unroll
    for (int j = 0; j < 4; ++j) {
      const int Rb = R0 + j * 1024;  // wave-uniform
      char* ldst = (char*)(&KV[b][0]) + Rb;
      if (Rb < 8192) {  // K region: row = key in chunk
        const int key = (Rb >> 7) + sKey8;
        const f16* src = kT + ((size_t)(head << 12) + keybase + ch * 64 + key) * DH +
                         ((sCol ^ (key & 7)) << 3);
        gload_lds16(src, ldst);
      } else {  // V region: row = d
        const int dd = ((Rb - 8192) >> 7) + sKey8;
        const f16* src = vv + ((size_t)(head * DH) + dd) * NPIX + keybase + ch * 64 +
                         ((sCol ^ (dd & 7)) << 3);
        gload_lds16(src, ldst);
      }
    }
  };

  stage(0, 0);
  __syncthreads();

  for (int ch = 0; ch < 16; ++ch) {
    const int b = ch & 1;
    if (ch < 15) stage(ch + 1, b ^ 1);  // issue early; drains under compute
    const f16* Kb = &KV[b][0];
    const f16* Vb = &KV[b][4096];
#pragma unroll
    for (int h = 0; h < 2; ++h) {  // two 32-key iterations per chunk
      f16x8 kf[2][2], vf[4];
#pragma unroll
      for (int nc = 0; nc < 2; ++nc) {
        const int key = h * 32 + nc * 16 + l15;
#pragma unroll
        for (int kc = 0; kc < 2; ++kc)
          kf[nc][kc] = *(const f16x8*)(Kb + key * 64 + (((kc * 4 + quad) ^ rx) << 3));
      }
#pragma unroll
      for (int c = 0; c < 4; ++c) {
        const int dd = c * 16 + l15;
        vf[c] = *(const f16x8*)(Vb + dd * 64 + (((h * 4 + quad) ^ rx) << 3));
      }
#pragma unroll
      for (int qt = 0; qt < 2; ++qt) {
        // S^T[key][q] = K @ Q'^T (q pre-scaled; C-layout row=key, col=q)
        f32x4 s0 = mfma_f16(kf[0][0], qf[qt][0], (f32x4){0.f, 0.f, 0.f, 0.f});
        s0 = mfma_f16(kf[0][1], qf[qt][1], s0);
        f32x4 s1 = mfma_f16(kf[1][0], qf[qt][0], (f32x4){0.f, 0.f, 0.f, 0.f});
        s1 = mfma_f16(kf[1][1], qf[qt][1], s1);
        // p = exp2(s'), no max subtraction (|s'| << 1)
        float p0[4], p1[4];
#pragma unroll
        for (int r = 0; r < 4; ++r) {
          p0[r] = __builtin_amdgcn_exp2f(s0[r]);
          p1[r] = __builtin_amdgcn_exp2f(s1[r]);
        }
        // per-lane lsum partial; quad-reduce deferred to epilogue
        ol[qt] += ((p0[0] + p0[1]) + (p0[2] + p0[3])) +
                  ((p1[0] + p1[1]) + (p1[2] + p1[3]));
        // P^T C-layout -> B-frag: pack pairs, 4 whole-dword bpermutes
        unsigned A0 = pk2(p0[0], p0[1]), B0 = pk2(p0[2], p0[3]);
        unsigned A1 = pk2(p1[0], p1[1]), B1 = pk2(p1[2], p1[3]);
        unsigned As = hiQuad ? A1 : A0;
        unsigned Bs = hiQuad ? B1 : B0;
        union { f16x8 v; unsigned u[4]; } pf;
        pf.u[0] = (unsigned)__builtin_amdgcn_ds_bpermute(srcA4, (int)As);
        pf.u[1] = (unsigned)__builtin_amdgcn_ds_bpermute(srcA4, (int)Bs);
        pf.u[2] = (unsigned)__builtin_amdgcn_ds_bpermute(srcB4, (int)As);
        pf.u[3] = (unsigned)__builtin_amdgcn_ds_bpermute(srcB4, (int)Bs);
        // O^T[d][q] += V^T @ P^T
#pragma unroll
        for (int c = 0; c < 4; ++c) o[qt][c] = mfma_f16(vf[c], pf.v, o[qt][c]);
      }
    }
    __syncthreads();  // staged writes visible + all waves done with buf b
  }

  // deferred lsum quad-reduce
#pragma unroll
  for (int qt = 0; qt < 2; ++qt) {
    ol[qt] += __shfl_xor(ol[qt], 16);
    ol[qt] += __shfl_xor(ol[qt], 32);
  }

  // store partials: Opart[split][qinst][d], Lpart[split][qinst]
#pragma unroll
  for (int qt = 0; qt < 2; ++qt) {
#pragma unroll
    for (int c = 0; c < 4; ++c)
#pragma unroll
      for (int r = 0; r < 4; ++r)
        Opart[((size_t)split * 32768 + qrow + qt * 16 + l15) * 64 + c * 16 + quad * 4 + r] =
            (PT)o[qt][c][r];
    if (quad == 0) Lpart[split * 32768 + qrow + qt * 16 + l15] = ol[qt];
  }
}

// ---------------- K3b: merge 4 key-split partials ----------------
// 131072 threads; thread tg owns floats [tg*16, tg*16+16) of each split plane
// (= qinst tg>>2, d-block (tg&3)*16) -> fully coalesced 16B loads/stores.
template <typename PT>
__global__ __launch_bounds__(256) void k_merge(const PT* __restrict__ Opart,
                                               const float* __restrict__ Lpart,
                                               f16* __restrict__ Ows) {
  const int tg = blockIdx.x * 256 + threadIdx.x;
  const int qi = tg >> 2;
  const size_t base = (size_t)tg * 16;
  float acc[16];
#pragma unroll
  for (int i = 0; i < 16; ++i) acc[i] = 0.f;
  float L = 0.f;
#pragma unroll
  for (int s = 0; s < 4; ++s) {
    const PT* p = Opart + (size_t)s * (32768 * 64) + base;
    if constexpr (sizeof(PT) == 4) {
      const float4* p4 = (const float4*)p;
      float4 v0 = p4[0], v1 = p4[1], v2 = p4[2], v3 = p4[3];
      acc[0] += v0.x; acc[1] += v0.y; acc[2] += v0.z; acc[3] += v0.w;
      acc[4] += v1.x; acc[5] += v1.y; acc[6] += v1.z; acc[7] += v1.w;
      acc[8] += v2.x; acc[9] += v2.y; acc[10] += v2.z; acc[11] += v2.w;
      acc[12] += v3.x; acc[13] += v3.y; acc[14] += v3.z; acc[15] += v3.w;
    } else {
      const f16x8* ph = (const f16x8*)p;
      f16x8 v0 = ph[0], v1 = ph[1];
#pragma unroll
      for (int i = 0; i < 8; ++i) {
        acc[i] += (float)v0[i];
        acc[8 + i] += (float)v1[i];
      }
    }
    L += Lpart[s * 32768 + qi];
  }
  union { f16x8 v[2]; f16 h[16]; } hv;
#pragma unroll
  for (int i = 0; i < 16; ++i) hv.h[i] = (f16)(acc[i] / L);
  *(f16x8*)(Ows + base) = hv.v[0];
  *(f16x8*)(Ows + base + 8) = hv.v[1];
}

// ---------------- K4: out projection + bias + residual ----------------
__global__ __launch_bounds__(256) void k_oproj(const f16* __restrict__ wout,
                                               const f16* __restrict__ Ows,
                                               const float* __restrict__ bout,
                                               const float* __restrict__ xn,
                                               float* __restrict__ out) {
  const int lane = threadIdx.x & 63, wave = threadIdx.x >> 6;
  const int l15 = lane & 15, quad = lane >> 4;
  const int mbase = blockIdx.y * 32 + (wave >> 1) * 16;
  const int pbase = blockIdx.x * 64 + (wave & 1) * 32;
  f32x4 acc[2];
  acc[0] = (f32x4){0.f, 0.f, 0.f, 0.f};
  acc[1] = (f32x4){0.f, 0.f, 0.f, 0.f};
#pragma unroll
  for (int kc = 0; kc < INNER / 32; ++kc) {
    f16x8 af = *(const f16x8*)(wout + (size_t)(mbase + l15) * INNER + kc * 32 + quad * 8);
    int i0 = kc * 32 + quad * 8;
    int head = i0 >> 6, d0 = i0 & 63;
#pragma unroll
    for (int pc = 0; pc < 2; ++pc) {
      f16x8 bfr = *(const f16x8*)(Ows + ((size_t)(head << 12) + pbase + pc * 16 + l15) * DH + d0);
      acc[pc] = mfma_f16(af, bfr, acc[pc]);
    }
  }
#pragma unroll
  for (int pc = 0; pc < 2; ++pc)
#pragma unroll
    for (int r = 0; r < 4; ++r) {
      int c = mbase + quad * 4 + r, p = pbase + pc * 16 + l15;
      out[c * NPIX + p] = acc[pc][r] + bout[c] + xn[c * NPIX + p];
    }
}

extern "C" void kernel_launch(void* const* d_in, const int* in_sizes, int n_in,
                              void* d_out, int out_size, void* d_ws, size_t ws_size,
                              hipStream_t stream) {
  (void)in_sizes; (void)n_in; (void)out_size;
  const float* x      = (const float*)d_in[0];
  const float* norm_w = (const float*)d_in[1];
  const float* w_qkv  = (const float*)d_in[2];
  const float* w_out  = (const float*)d_in[3];
  const float* b_out  = (const float*)d_in[4];
  float* out = (float*)d_out;

  char* ws = (char*)d_ws;
  float* xn    = (float*)(ws);                 // 4 MB
  f16* xnT     = (f16*)(ws + (4u << 20));      // 2 MB
  f16* qT      = (f16*)(ws + (6u << 20));      // 4 MB  [head][p][d], pre-scaled
  f16* kT      = (f16*)(ws + (10u << 20));     // 4 MB  [head][p][d]
  f16* vv      = (f16*)(ws + (14u << 20));     // 4 MB  [head*64+d][p]
  f16* Ows     = (f16*)(ws + (18u << 20));     // 4 MB  [head][p][d]
  f16* wqkv_h  = (f16*)(ws + (22u << 20));             // 0.75 MB
  f16* wout_h  = (f16*)(ws + (22u << 20) + 786432);    // 0.25 MB

  const int n1 = 3 * INNER * CIN, n2 = CIN * INNER;
  hipLaunchKernelGGL(k_cvt2, dim3((n1 + n2 + 255) / 256), dim3(256), 0, stream,
                     w_qkv, n1, w_out, n2, wqkv_h);
  hipLaunchKernelGGL(k_rmsnorm, dim3(NPIX / 16), dim3(256), 0, stream, x, norm_w, xn, xnT);
  hipLaunchKernelGGL(k_qkv, dim3(NPIX / 128, 1536 / 64), dim3(256), 0, stream,
                     wqkv_h, xnT, qT, kT, vv);

  // key-split partials: Opart[4][32768][64] + Lpart[4][32768] @ ws+24MB.
  // f32 path needs 56.5 MB of ws; fall back to f16 partials (40.5 MB) if short.
  const size_t OPLANE = (size_t)32768 * 64;
  char* pbase = ws + (24u << 20);
  if (ws_size >= (24u << 20) + OPLANE * 4 * sizeof(float) + 4 * 32768 * sizeof(float)) {
    float* Op = (float*)pbase;
    float* Lp = (float*)(pbase + OPLANE * 4 * sizeof(float));
    hipLaunchKernelGGL((k_attn<float>), dim3(1024), dim3(256), 0, stream,
                       qT, kT, vv, Op, Lp);
    hipLaunchKernelGGL((k_merge<float>), dim3(512), dim3(256), 0, stream,
                       Op, Lp, Ows);
  } else {
    f16* Op = (f16*)pbase;
    float* Lp = (float*)(pbase + OPLANE * 4 * sizeof(f16));
    hipLaunchKernelGGL((k_attn<f16>), dim3(1024), dim3(256), 0, stream,
                       qT, kT, vv, Op, Lp);
    hipLaunchKernelGGL((k_merge<f16>), dim3(512), dim3(256), 0, stream,
                       Op, Lp, Ows);
  }

  hipLaunchKernelGGL(k_oproj, dim3(NPIX / 64, CIN / 32), dim3(256), 0, stream,
                     wout_h, Ows, b_out, xn, out);
}

// Round 5
// 153.440 us; speedup vs baseline: 1.4489x; 1.0091x over previous
//
#include <hip/hip_runtime.h>

// FullAttention fused block on gfx950. fp32 harness I/O, fp16 MFMA internally.
//
// Pipeline:
//   k_cvt2    : w_qkv + w_out fp32 -> f16 (single launch)
//   k_rmsnorm : x[C][N] -> xn[C][N] fp32 (residual) + xnT[N][C] f16
//   k_qkv     : GEMM 1536x256x4096 -> qT/kT [head][p][d] f16 (q pre-scaled by
//               0.125*log2e), vv [d'][p] f16
//   k_attn    : flash attention. r4 PMC: SQ_LDS_BANK_CONFLICT == #bpermutes
//               exactly; LDS pipe (frag reads 49k + bperm 24k + staging 8k
//               cyc/CU) was ~65% of the wall. This round: (a) P^T transpose
//               via v_permlane16/32_swap + cndmask (VALU) instead of 4
//               ds_bpermute (LDS) -- formally lane-equivalent network;
//               (b) 64 q/wave (frag-read volume halves: reads scale 1/qpw);
//               (c) staging addrs hoisted to incrementing per-lane pointers.
//               4 waves x 64 q = 256 q/block, 4-way key split, grid 512,
//               2 blocks/CU. head = bid&7 keeps one head per XCD L2.
//   k_merge   : sum 4 key-split partials, divide by lsum -> Ows f16
//   k_oproj   : GEMM 256x512x4096 + bias + residual -> fp32 out
//
// MFMA 16x16x32 layouts (HW-verified per guide):
//   A-frag: lane holds A[m=lane&15][k=quad*8+j], j=0..7
//   B-frag: lane holds B[k=quad*8+j][n=lane&15]
//   C/D   : lane holds D[row=quad*4+reg][col=lane&15], reg=0..3

#define NPIX 4096
#define CIN 256
#define INNER 512
#define NHEAD 8
#define DH 64

typedef _Float16 f16;
typedef __attribute__((ext_vector_type(8))) _Float16 f16x8;
typedef __attribute__((ext_vector_type(4))) float f32x4;

static __device__ __forceinline__ f32x4 mfma_f16(f16x8 a, f16x8 b, f32x4 c) {
  return __builtin_amdgcn_mfma_f32_16x16x32_f16(a, b, c, 0, 0, 0);
}

static __device__ __forceinline__ unsigned pk2(float lo, float hi) {
  return __builtin_bit_cast(unsigned, __builtin_amdgcn_cvt_pkrtz(lo, hi));
}

// async global->LDS, 16 B per lane; LDS dest = wave-uniform base + lane*16
static __device__ __forceinline__ void gload_lds16(const void* g, void* l) {
  __builtin_amdgcn_global_load_lds(
      (const __attribute__((address_space(1))) unsigned*)g,
      (__attribute__((address_space(3))) unsigned*)l, 16, 0, 0);
}

// ---------------- K0: fp32 -> f16, two sources, contiguous dst ----------------
__global__ __launch_bounds__(256) void k_cvt2(const float* __restrict__ a1, int n1,
                                              const float* __restrict__ a2, int n2,
                                              f16* __restrict__ b) {
  int i = blockIdx.x * 256 + threadIdx.x;
  if (i < n1) b[i] = (f16)a1[i];
  else if (i < n1 + n2) b[i] = (f16)a2[i - n1];
}

// ---------------- K1: RMSNorm (256 blocks, 16 pixels each) ----------------
__global__ __launch_bounds__(256) void k_rmsnorm(const float* __restrict__ x,
                                                 const float* __restrict__ w,
                                                 float* __restrict__ xn,
                                                 f16* __restrict__ xnT) {
  const int pi = threadIdx.x & 15, cs = threadIdx.x >> 4;
  const int p = blockIdx.x * 16 + pi;
  __shared__ float red[16][16];
  float xv[16];
  float ss = 0.f;
#pragma unroll
  for (int i = 0; i < 16; ++i) {
    xv[i] = x[(cs * 16 + i) * NPIX + p];
    ss += xv[i] * xv[i];
  }
  red[cs][pi] = ss;
  __syncthreads();
  float tot = 0.f;
#pragma unroll
  for (int s = 0; s < 16; ++s) tot += red[s][pi];
  float inv = 16.0f / fmaxf(sqrtf(tot), 1e-12f);  // sqrt(256)=16
  union { f16x8 v[2]; f16 h[16]; } hv;
#pragma unroll
  for (int i = 0; i < 16; ++i) {
    int c = cs * 16 + i;
    float v = xv[i] * inv * w[c];
    xn[c * NPIX + p] = v;
    hv.h[i] = (f16)v;
  }
  *(f16x8*)(xnT + (size_t)p * CIN + cs * 16) = hv.v[0];
  *(f16x8*)(xnT + (size_t)p * CIN + cs * 16 + 8) = hv.v[1];
}

// ---------------- K2: QKV GEMM, wave tile 32x64 ----------------
__global__ __launch_bounds__(256) void k_qkv(const f16* __restrict__ wqkv,
                                             const f16* __restrict__ xnT,
                                             f16* __restrict__ qT,
                                             f16* __restrict__ kT,
                                             f16* __restrict__ vv) {
  const int lane = threadIdx.x & 63, wave = threadIdx.x >> 6;
  const int l15 = lane & 15, quad = lane >> 4;
  const int obase = blockIdx.y * 64 + (wave >> 1) * 32;
  const int pbase = blockIdx.x * 128 + (wave & 1) * 64;
  const int sect = blockIdx.y >> 3;  // 0=q, 1=k, 2=v
  f32x4 acc[8];
#pragma unroll
  for (int i = 0; i < 8; ++i) acc[i] = (f32x4){0.f, 0.f, 0.f, 0.f};
#pragma unroll
  for (int kc = 0; kc < CIN / 32; ++kc) {
    f16x8 af[2], bfr[4];
#pragma unroll
    for (int oc = 0; oc < 2; ++oc)
      af[oc] = *(const f16x8*)(wqkv + (size_t)(obase + oc * 16 + l15) * CIN + kc * 32 + quad * 8);
#pragma unroll
    for (int pc = 0; pc < 4; ++pc)
      bfr[pc] = *(const f16x8*)(xnT + (size_t)(pbase + pc * 16 + l15) * CIN + kc * 32 + quad * 8);
    if (sect < 2) {
#pragma unroll
      for (int pc = 0; pc < 4; ++pc)
#pragma unroll
        for (int oc = 0; oc < 2; ++oc)
          acc[pc * 2 + oc] = mfma_f16(bfr[pc], af[oc], acc[pc * 2 + oc]);
    } else {
#pragma unroll
      for (int oc = 0; oc < 2; ++oc)
#pragma unroll
        for (int pc = 0; pc < 4; ++pc)
          acc[oc * 4 + pc] = mfma_f16(af[oc], bfr[pc], acc[oc * 4 + pc]);
    }
  }
  if (sect < 2) {
    f16* dst = (sect == 0) ? qT : kT;
    const float sc = (sect == 0) ? 0.18033688f : 1.0f;  // 0.125*log2(e)
    const int head = blockIdx.y & 7;
    const int dd = (wave >> 1) * 32;
#pragma unroll
    for (int pc = 0; pc < 4; ++pc)
#pragma unroll
      for (int oc = 0; oc < 2; ++oc)
#pragma unroll
        for (int r = 0; r < 4; ++r) {
          int p = pbase + pc * 16 + quad * 4 + r;
          dst[((size_t)(head << 12) + p) * DH + dd + oc * 16 + l15] =
              (f16)(acc[pc * 2 + oc][r] * sc);
        }
  } else {
#pragma unroll
    for (int oc = 0; oc < 2; ++oc)
#pragma unroll
      for (int r = 0; r < 4; ++r) {
        int o = obase + oc * 16 + quad * 4 + r - 2 * INNER;
#pragma unroll
        for (int pc = 0; pc < 4; ++pc)
          vv[(size_t)o * NPIX + pbase + pc * 16 + l15] = (f16)acc[oc * 4 + pc][r];
      }
  }
}

// ---------------- K3: flash attention (LDS-staged K/V, q-split waves) --------
// grid 512 x 256 threads. bid -> head = bid&7, split = (bid>>3)&3 (key
// quarter), qb = bid>>5 (0..15). Block: 4 waves x 64 q = 256 q; keys
// [split*1024, +1024) staged through LDS in 16 double-buffered 64-key chunks.
// LDS swizzle: 16B-col ^= (row&7) on the pre-swizzled global SOURCE and on
// the ds_read address (global_load_lds writes linearly) -> conflict-free.
// P^T -> B-frag transpose: v_permlane16/32_swap + cndmask (pure VALU; the
// r4 bpermute version put ~24k cyc/CU + all measured bank conflicts on the
// LDS pipe). Staging addresses: 4 per-lane pointers, +step per chunk.
template <typename PT>
__global__ __launch_bounds__(256, 2) void k_attn(const f16* __restrict__ qT,
                                                 const f16* __restrict__ kT,
                                                 const f16* __restrict__ vv,
                                                 PT* __restrict__ Opart,
                                                 float* __restrict__ Lpart) {
  const int bid = blockIdx.x;
  const int head = bid & 7, split = (bid >> 3) & 3, qb = bid >> 5;
  const int tid = threadIdx.x;
  const int wave = tid >> 6, lane = tid & 63;
  const int l15 = lane & 15, quad = lane >> 4;
  const int keybase = split * 1024;

  __shared__ f16 KV[2][8192];  // per buf: [0,4096) = K chunk, [4096,8192) = V

  // Q B-frags: B[k=d][n=q] from qT[head][q][d]
  const int qrow = (head << 12) + qb * 256 + wave * 64;
  f16x8 qf[4][2];
#pragma unroll
  for (int qt = 0; qt < 4; ++qt)
#pragma unroll
    for (int kc = 0; kc < 2; ++kc)
      qf[qt][kc] = *(const f16x8*)(qT + (size_t)(qrow + qt * 16 + l15) * DH + kc * 32 + quad * 8);

  f32x4 o[4][4];
  float ol[4] = {0.f, 0.f, 0.f, 0.f};
#pragma unroll
  for (int qt = 0; qt < 4; ++qt)
#pragma unroll
    for (int c = 0; c < 4; ++c) o[qt][c] = (f32x4){0.f, 0.f, 0.f, 0.f};

  const int rx = l15 & 7;  // read-side swizzle xor (row&7 == l15&7)
  const bool qodd = (quad & 1) != 0;

  // staging pointers: waves 0,1 stage K rows (64 keys x 64 d), waves 2,3
  // stage V rows (64 d x 64 keys). Swizzle is chunk-invariant -> pointers
  // just advance by a wave-uniform step each chunk.
  const int sRow8 = lane >> 3, sCol = lane & 7;
  const f16* sp[4];
  const int step = (wave < 2) ? 64 * DH : 64;  // f16 elements per chunk
#pragma unroll
  for (int j = 0; j < 4; ++j) {
    const int Rb = wave * 4096 + j * 1024;  // LDS byte offset of this region
    if (wave < 2) {
      const int key = (Rb >> 7) + sRow8;  // 0..63
      sp[j] = kT + ((size_t)(head << 12) + keybase + key) * DH + ((sCol ^ (key & 7)) << 3);
    } else {
      const int dd = ((Rb - 8192) >> 7) + sRow8;  // 0..63
      sp[j] = vv + ((size_t)(head * DH) + dd) * NPIX + keybase + ((sCol ^ (dd & 7)) << 3);
    }
  }
  auto stage = [&](int b) {
    char* base = (char*)(&KV[b][0]) + wave * 4096;
#pragma unroll
    for (int j = 0; j < 4; ++j) {
      gload_lds16(sp[j], base + j * 1024);
      sp[j] += step;
    }
  };

  stage(0);
  __syncthreads();

  for (int ch = 0; ch < 16; ++ch) {
    const int b = ch & 1;
    if (ch < 15) stage(b ^ 1);  // issue early; drains under compute
    const f16* Kb = &KV[b][0];
    const f16* Vb = &KV[b][4096];
#pragma unroll
    for (int h = 0; h < 2; ++h) {  // two 32-key iterations per chunk
      f16x8 kf[2][2], vf[4];
#pragma unroll
      for (int nc = 0; nc < 2; ++nc) {
        const int key = h * 32 + nc * 16 + l15;
#pragma unroll
        for (int kc = 0; kc < 2; ++kc)
          kf[nc][kc] = *(const f16x8*)(Kb + key * 64 + (((kc * 4 + quad) ^ rx) << 3));
      }
#pragma unroll
      for (int c = 0; c < 4; ++c) {
        const int dd = c * 16 + l15;
        vf[c] = *(const f16x8*)(Vb + dd * 64 + (((h * 4 + quad) ^ rx) << 3));
      }
#pragma unroll
      for (int qt = 0; qt < 4; ++qt) {
        // S^T[key][q] = K @ Q'^T (q pre-scaled; C-layout row=key, col=q)
        f32x4 s0 = mfma_f16(kf[0][0], qf[qt][0], (f32x4){0.f, 0.f, 0.f, 0.f});
        s0 = mfma_f16(kf[0][1], qf[qt][1], s0);
        f32x4 s1 = mfma_f16(kf[1][0], qf[qt][0], (f32x4){0.f, 0.f, 0.f, 0.f});
        s1 = mfma_f16(kf[1][1], qf[qt][1], s1);
        // p = exp2(s'), no max subtraction (|s'| << 1)
        float p0[4], p1[4];
#pragma unroll
        for (int r = 0; r < 4; ++r) {
          p0[r] = __builtin_amdgcn_exp2f(s0[r]);
          p1[r] = __builtin_amdgcn_exp2f(s1[r]);
        }
        // per-lane lsum partial; quad-reduce deferred to epilogue
        ol[qt] += ((p0[0] + p0[1]) + (p0[2] + p0[3])) +
                  ((p1[0] + p1[1]) + (p1[2] + p1[3]));
        // P^T C-layout -> B-frag, pure VALU (lane-equivalent to the old
        // 4x ds_bpermute network):
        //   P16(A0,A1): A0' = [A0q0,A1q0,A0q2,A1q2], A1' = [A0q1,A1q1,A0q3,A1q3]
        //   P32(X,X)  : lo-dup / hi-dup; select by quad parity.
        unsigned A0 = pk2(p0[0], p0[1]), B0 = pk2(p0[2], p0[3]);
        unsigned A1 = pk2(p1[0], p1[1]), B1 = pk2(p1[2], p1[3]);
        asm("v_permlane16_swap_b32 %0, %1" : "+v"(A0), "+v"(A1));
        asm("v_permlane16_swap_b32 %0, %1" : "+v"(B0), "+v"(B1));
        unsigned xa = A0, ya = A0;
        asm("v_permlane32_swap_b32 %0, %1" : "+v"(xa), "+v"(ya));
        unsigned xa2 = A1, ya2 = A1;
        asm("v_permlane32_swap_b32 %0, %1" : "+v"(xa2), "+v"(ya2));
        unsigned xb = B0, yb = B0;
        asm("v_permlane32_swap_b32 %0, %1" : "+v"(xb), "+v"(yb));
        unsigned xb2 = B1, yb2 = B1;
        asm("v_permlane32_swap_b32 %0, %1" : "+v"(xb2), "+v"(yb2));
        union { f16x8 v; unsigned u[4]; } pf;
        pf.u[0] = qodd ? ya : xa;
        pf.u[1] = qodd ? yb : xb;
        pf.u[2] = qodd ? ya2 : xa2;
        pf.u[3] = qodd ? yb2 : xb2;
        // O^T[d][q] += V^T @ P^T
#pragma unroll
        for (int c = 0; c < 4; ++c) o[qt][c] = mfma_f16(vf[c], pf.v, o[qt][c]);
      }
    }
    __syncthreads();  // staged writes visible + all waves done with buf b
  }

  // deferred lsum quad-reduce
#pragma unroll
  for (int qt = 0; qt < 4; ++qt) {
    ol[qt] += __shfl_xor(ol[qt], 16);
    ol[qt] += __shfl_xor(ol[qt], 32);
  }

  // store partials: Opart[split][qinst][d], Lpart[split][qinst]
#pragma unroll
  for (int qt = 0; qt < 4; ++qt) {
#pragma unroll
    for (int c = 0; c < 4; ++c) {
      const size_t off =
          ((size_t)split * 32768 + qrow + qt * 16 + l15) * 64 + c * 16 + quad * 4;
      if constexpr (sizeof(PT) == 4) {
        *(float4*)(Opart + off) =
            make_float4(o[qt][c][0], o[qt][c][1], o[qt][c][2], o[qt][c][3]);
      } else {
#pragma unroll
        for (int r = 0; r < 4; ++r) Opart[off + r] = (PT)o[qt][c][r];
      }
    }
    if (quad == 0) Lpart[split * 32768 + qrow + qt * 16 + l15] = ol[qt];
  }
}

// ---------------- K3b: merge 4 key-split partials ----------------
template <typename PT>
__global__ __launch_bounds__(256) void k_merge(const PT* __restrict__ Opart,
                                               const float* __restrict__ Lpart,
                                               f16* __restrict__ Ows) {
  const int tg = blockIdx.x * 256 + threadIdx.x;
  const int qi = tg >> 2;
  const size_t base = (size_t)tg * 16;
  float acc[16];
#pragma unroll
  for (int i = 0; i < 16; ++i) acc[i] = 0.f;
  float L = 0.f;
#pragma unroll
  for (int s = 0; s < 4; ++s) {
    const PT* p = Opart + (size_t)s * (32768 * 64) + base;
    if constexpr (sizeof(PT) == 4) {
      const float4* p4 = (const float4*)p;
      float4 v0 = p4[0], v1 = p4[1], v2 = p4[2], v3 = p4[3];
      acc[0] += v0.x; acc[1] += v0.y; acc[2] += v0.z; acc[3] += v0.w;
      acc[4] += v1.x; acc[5] += v1.y; acc[6] += v1.z; acc[7] += v1.w;
      acc[8] += v2.x; acc[9] += v2.y; acc[10] += v2.z; acc[11] += v2.w;
      acc[12] += v3.x; acc[13] += v3.y; acc[14] += v3.z; acc[15] += v3.w;
    } else {
      const f16x8* ph = (const f16x8*)p;
      f16x8 v0 = ph[0], v1 = ph[1];
#pragma unroll
      for (int i = 0; i < 8; ++i) {
        acc[i] += (float)v0[i];
        acc[8 + i] += (float)v1[i];
      }
    }
    L += Lpart[s * 32768 + qi];
  }
  union { f16x8 v[2]; f16 h[16]; } hv;
#pragma unroll
  for (int i = 0; i < 16; ++i) hv.h[i] = (f16)(acc[i] / L);
  *(f16x8*)(Ows + base) = hv.v[0];
  *(f16x8*)(Ows + base + 8) = hv.v[1];
}

// ---------------- K4: out projection + bias + residual ----------------
__global__ __launch_bounds__(256) void k_oproj(const f16* __restrict__ wout,
                                               const f16* __restrict__ Ows,
                                               const float* __restrict__ bout,
                                               const float* __restrict__ xn,
                                               float* __restrict__ out) {
  const int lane = threadIdx.x & 63, wave = threadIdx.x >> 6;
  const int l15 = lane & 15, quad = lane >> 4;
  const int mbase = blockIdx.y * 32 + (wave >> 1) * 16;
  const int pbase = blockIdx.x * 64 + (wave & 1) * 32;
  f32x4 acc[2];
  acc[0] = (f32x4){0.f, 0.f, 0.f, 0.f};
  acc[1] = (f32x4){0.f, 0.f, 0.f, 0.f};
#pragma unroll
  for (int kc = 0; kc < INNER / 32; ++kc) {
    f16x8 af = *(const f16x8*)(wout + (size_t)(mbase + l15) * INNER + kc * 32 + quad * 8);
    int i0 = kc * 32 + quad * 8;
    int head = i0 >> 6, d0 = i0 & 63;
#pragma unroll
    for (int pc = 0; pc < 2; ++pc) {
      f16x8 bfr = *(const f16x8*)(Ows + ((size_t)(head << 12) + pbase + pc * 16 + l15) * DH + d0);
      acc[pc] = mfma_f16(af, bfr, acc[pc]);
    }
  }
#pragma unroll
  for (int pc = 0; pc < 2; ++pc)
#pragma unroll
    for (int r = 0; r < 4; ++r) {
      int c = mbase + quad * 4 + r, p = pbase + pc * 16 + l15;
      out[c * NPIX + p] = acc[pc][r] + bout[c] + xn[c * NPIX + p];
    }
}

extern "C" void kernel_launch(void* const* d_in, const int* in_sizes, int n_in,
                              void* d_out, int out_size, void* d_ws, size_t ws_size,
                              hipStream_t stream) {
  (void)in_sizes; (void)n_in; (void)out_size;
  const float* x      = (const float*)d_in[0];
  const float* norm_w = (const float*)d_in[1];
  const float* w_qkv  = (const float*)d_in[2];
  const float* w_out  = (const float*)d_in[3];
  const float* b_out  = (const float*)d_in[4];
  float* out = (float*)d_out;

  char* ws = (char*)d_ws;
  float* xn    = (float*)(ws);                 // 4 MB
  f16* xnT     = (f16*)(ws + (4u << 20));      // 2 MB
  f16* qT      = (f16*)(ws + (6u << 20));      // 4 MB  [head][p][d], pre-scaled
  f16* kT      = (f16*)(ws + (10u << 20));     // 4 MB  [head][p][d]
  f16* vv      = (f16*)(ws + (14u << 20));     // 4 MB  [head*64+d][p]
  f16* Ows     = (f16*)(ws + (18u << 20));     // 4 MB  [head][p][d]
  f16* wqkv_h  = (f16*)(ws + (22u << 20));             // 0.75 MB
  f16* wout_h  = (f16*)(ws + (22u << 20) + 786432);    // 0.25 MB

  const int n1 = 3 * INNER * CIN, n2 = CIN * INNER;
  hipLaunchKernelGGL(k_cvt2, dim3((n1 + n2 + 255) / 256), dim3(256), 0, stream,
                     w_qkv, n1, w_out, n2, wqkv_h);
  hipLaunchKernelGGL(k_rmsnorm, dim3(NPIX / 16), dim3(256), 0, stream, x, norm_w, xn, xnT);
  hipLaunchKernelGGL(k_qkv, dim3(NPIX / 128, 1536 / 64), dim3(256), 0, stream,
                     wqkv_h, xnT, qT, kT, vv);

  // key-split partials: Opart[4][32768][64] + Lpart[4][32768] @ ws+24MB.
  const size_t OPLANE = (size_t)32768 * 64;
  char* pbase = ws + (24u << 20);
  if (ws_size >= (24u << 20) + OPLANE * 4 * sizeof(float) + 4 * 32768 * sizeof(float)) {
    float* Op = (float*)pbase;
    float* Lp = (float*)(pbase + OPLANE * 4 * sizeof(float));
    hipLaunchKernelGGL((k_attn<float>), dim3(512), dim3(256), 0, stream,
                       qT, kT, vv, Op, Lp);
    hipLaunchKernelGGL((k_merge<float>), dim3(512), dim3(256), 0, stream,
                       Op, Lp, Ows);
  } else {
    f16* Op = (f16*)pbase;
    float* Lp = (float*)(pbase + OPLANE * 4 * sizeof(f16));
    hipLaunchKernelGGL((k_attn<f16>), dim3(512), dim3(256), 0, stream,
                       qT, kT, vv, Op, Lp);
    hipLaunchKernelGGL((k_merge<f16>), dim3(512), dim3(256), 0, stream,
                       Op, Lp, Ows);
  }

  hipLaunchKernelGGL(k_oproj, dim3(NPIX / 64, CIN / 32), dim3(256), 0, stream,
                     wout_h, Ows, b_out, xn, out);
}

// Round 6
// 150.962 us; speedup vs baseline: 1.4726x; 1.0164x over previous
//
#include <hip/hip_runtime.h>

// FullAttention fused block on gfx950. fp32 harness I/O, fp16 MFMA internally.
//
// Pipeline (5 launches):
//   k_prep    : fused [rmsnorm: x[C][N] -> xn fp32 + xnT[N][C] f16] +
//               [w_qkv,w_out fp32 -> f16]; block-range split
//   k_qkv     : GEMM 1536x256x4096 -> qT/kT [head][p][d] f16 (q pre-scaled by
//               0.125*log2e), vv [d'][p] f16
//   k_attn    : flash attention. Ladder: r4 showed LDS pipe 80k cyc/CU (frag
//               reads 49k + bperm 24k + staging 8k) at 4 waves/SIMD; r5
//               (qpw=64) halved frag reads + killed bperm conflicts (PMC: 0)
//               but 64-AGPR acc -> 2 waves/SIMD, lost overlap, flat. This
//               round: qpw=32 (4 waves/SIMD, 32-AGPR acc) + permlane VALU
//               transpose (keeps LDS at ~57k) + f16 partials (write 16MB).
//   k_merge   : sum 4 key-split f16 partials, scale by 1/lsum -> Ows f16
//   k_oproj   : GEMM 256x512x4096 + bias + residual -> fp32 out
//
// MFMA 16x16x32 layouts (HW-verified per guide):
//   A-frag: lane holds A[m=lane&15][k=quad*8+j], j=0..7
//   B-frag: lane holds B[k=quad*8+j][n=lane&15]
//   C/D   : lane holds D[row=quad*4+reg][col=lane&15], reg=0..3

#define NPIX 4096
#define CIN 256
#define INNER 512
#define NHEAD 8
#define DH 64

typedef _Float16 f16;
typedef __attribute__((ext_vector_type(8))) _Float16 f16x8;
typedef __attribute__((ext_vector_type(4))) _Float16 f16x4;
typedef __attribute__((ext_vector_type(4))) float f32x4;

static __device__ __forceinline__ f32x4 mfma_f16(f16x8 a, f16x8 b, f32x4 c) {
  return __builtin_amdgcn_mfma_f32_16x16x32_f16(a, b, c, 0, 0, 0);
}

static __device__ __forceinline__ unsigned pk2(float lo, float hi) {
  return __builtin_bit_cast(unsigned, __builtin_amdgcn_cvt_pkrtz(lo, hi));
}

// async global->LDS, 16 B per lane; LDS dest = wave-uniform base + lane*16
static __device__ __forceinline__ void gload_lds16(const void* g, void* l) {
  __builtin_amdgcn_global_load_lds(
      (const __attribute__((address_space(1))) unsigned*)g,
      (__attribute__((address_space(3))) unsigned*)l, 16, 0, 0);
}

// ---------------- K0: fused RMSNorm + weight cvt ----------------
// blocks [0,512): rmsnorm, 8 pixels each (2 blocks/CU -> 8 waves/CU, vs the
// old 256-block/1-per-CU config). blocks [512,2560): fp32->f16 weight cvt.
__global__ __launch_bounds__(256) void k_prep(
    const float* __restrict__ x, const float* __restrict__ w,
    float* __restrict__ xn, f16* __restrict__ xnT,
    const float* __restrict__ w1, int n1,
    const float* __restrict__ w2, int n2, f16* __restrict__ wh) {
  const int b = blockIdx.x;
  if (b < NPIX / 8) {
    const int pi = threadIdx.x & 7, cs = threadIdx.x >> 3;  // 8 px x 32 ch-grp
    const int p = b * 8 + pi;
    __shared__ float red[32][8];
    float xv[8];
    float ss = 0.f;
#pragma unroll
    for (int i = 0; i < 8; ++i) {
      xv[i] = x[(cs * 8 + i) * NPIX + p];
      ss += xv[i] * xv[i];
    }
    red[cs][pi] = ss;
    __syncthreads();
    float tot = 0.f;
#pragma unroll
    for (int s = 0; s < 32; ++s) tot += red[s][pi];
    float inv = 16.0f / fmaxf(sqrtf(tot), 1e-12f);  // sqrt(256)=16
    union { f16x8 v; f16 h[8]; } hv;
#pragma unroll
    for (int i = 0; i < 8; ++i) {
      int c = cs * 8 + i;
      float v = xv[i] * inv * w[c];
      xn[c * NPIX + p] = v;
      hv.h[i] = (f16)v;
    }
    *(f16x8*)(xnT + (size_t)p * CIN + cs * 8) = hv.v;
  } else {
    int i = (b - NPIX / 8) * 256 + threadIdx.x;
    if (i < n1) wh[i] = (f16)w1[i];
    else if (i < n1 + n2) wh[i] = (f16)w2[i - n1];
  }
}

// ---------------- K2: QKV GEMM, wave tile 32x64 ----------------
__global__ __launch_bounds__(256) void k_qkv(const f16* __restrict__ wqkv,
                                             const f16* __restrict__ xnT,
                                             f16* __restrict__ qT,
                                             f16* __restrict__ kT,
                                             f16* __restrict__ vv) {
  const int lane = threadIdx.x & 63, wave = threadIdx.x >> 6;
  const int l15 = lane & 15, quad = lane >> 4;
  const int obase = blockIdx.y * 64 + (wave >> 1) * 32;
  const int pbase = blockIdx.x * 128 + (wave & 1) * 64;
  const int sect = blockIdx.y >> 3;  // 0=q, 1=k, 2=v
  f32x4 acc[8];
#pragma unroll
  for (int i = 0; i < 8; ++i) acc[i] = (f32x4){0.f, 0.f, 0.f, 0.f};
#pragma unroll
  for (int kc = 0; kc < CIN / 32; ++kc) {
    f16x8 af[2], bfr[4];
#pragma unroll
    for (int oc = 0; oc < 2; ++oc)
      af[oc] = *(const f16x8*)(wqkv + (size_t)(obase + oc * 16 + l15) * CIN + kc * 32 + quad * 8);
#pragma unroll
    for (int pc = 0; pc < 4; ++pc)
      bfr[pc] = *(const f16x8*)(xnT + (size_t)(pbase + pc * 16 + l15) * CIN + kc * 32 + quad * 8);
    if (sect < 2) {
#pragma unroll
      for (int pc = 0; pc < 4; ++pc)
#pragma unroll
        for (int oc = 0; oc < 2; ++oc)
          acc[pc * 2 + oc] = mfma_f16(bfr[pc], af[oc], acc[pc * 2 + oc]);
    } else {
#pragma unroll
      for (int oc = 0; oc < 2; ++oc)
#pragma unroll
        for (int pc = 0; pc < 4; ++pc)
          acc[oc * 4 + pc] = mfma_f16(af[oc], bfr[pc], acc[oc * 4 + pc]);
    }
  }
  if (sect < 2) {
    f16* dst = (sect == 0) ? qT : kT;
    const float sc = (sect == 0) ? 0.18033688f : 1.0f;  // 0.125*log2(e)
    const int head = blockIdx.y & 7;
    const int dd = (wave >> 1) * 32;
#pragma unroll
    for (int pc = 0; pc < 4; ++pc)
#pragma unroll
      for (int oc = 0; oc < 2; ++oc)
#pragma unroll
        for (int r = 0; r < 4; ++r) {
          int p = pbase + pc * 16 + quad * 4 + r;
          dst[((size_t)(head << 12) + p) * DH + dd + oc * 16 + l15] =
              (f16)(acc[pc * 2 + oc][r] * sc);
        }
  } else {
#pragma unroll
    for (int oc = 0; oc < 2; ++oc)
#pragma unroll
      for (int r = 0; r < 4; ++r) {
        int o = obase + oc * 16 + quad * 4 + r - 2 * INNER;
#pragma unroll
        for (int pc = 0; pc < 4; ++pc)
          vv[(size_t)o * NPIX + pbase + pc * 16 + l15] = (f16)acc[oc * 4 + pc][r];
      }
  }
}

// ---------------- K3: flash attention (LDS-staged K/V, q-split waves) --------
// grid 1024 x 256 threads. bid -> head = bid&7 (one head per XCD L2), split =
// (bid>>3)&3 (key quarter), qb = bid>>5 (0..31). Block: 4 waves x 32 q; keys
// [split*1024, +1024) staged through LDS in 16 double-buffered 64-key chunks.
// LDS swizzle: 16B-col ^= (row&7) on the pre-swizzled global SOURCE and on
// the ds_read address (global_load_lds writes linearly) -> conflict-free
// (PMC r5: SQ_LDS_BANK_CONFLICT = 0). P^T -> B-frag transpose: pure-VALU
// permlane16/32_swap network (r5). qpw=32 -> 32-AGPR acc, 4 blocks/CU,
// 4 waves/SIMD (r4-verified occupancy) for inter-pipe overlap.
__global__ __launch_bounds__(256, 4) void k_attn(const f16* __restrict__ qT,
                                                 const f16* __restrict__ kT,
                                                 const f16* __restrict__ vv,
                                                 f16* __restrict__ Opart,
                                                 float* __restrict__ Lpart) {
  const int bid = blockIdx.x;
  const int head = bid & 7, split = (bid >> 3) & 3, qb = bid >> 5;
  const int tid = threadIdx.x;
  const int wave = tid >> 6, lane = tid & 63;
  const int l15 = lane & 15, quad = lane >> 4;
  const int keybase = split * 1024;

  __shared__ f16 KV[2][8192];  // per buf: [0,4096) = K chunk, [4096,8192) = V

  // Q B-frags: B[k=d][n=q] from qT[head][q][d]
  const int qrow = (head << 12) + qb * 128 + wave * 32;
  f16x8 qf[2][2];
#pragma unroll
  for (int qt = 0; qt < 2; ++qt)
#pragma unroll
    for (int kc = 0; kc < 2; ++kc)
      qf[qt][kc] = *(const f16x8*)(qT + (size_t)(qrow + qt * 16 + l15) * DH + kc * 32 + quad * 8);

  f32x4 o[2][4];
  float ol[2] = {0.f, 0.f};
#pragma unroll
  for (int qt = 0; qt < 2; ++qt)
#pragma unroll
    for (int c = 0; c < 4; ++c) o[qt][c] = (f32x4){0.f, 0.f, 0.f, 0.f};

  const int rx = l15 & 7;  // read-side swizzle xor (row&7 == l15&7)
  const bool qodd = (quad & 1) != 0;

  // staging pointers: waves 0,1 stage K rows (64 keys x 64 d), waves 2,3
  // stage V rows (64 d x 64 keys). Swizzle is chunk-invariant -> pointers
  // advance by a wave-uniform step each chunk.
  const int sRow8 = lane >> 3, sCol = lane & 7;
  const f16* sp[4];
  const int step = (wave < 2) ? 64 * DH : 64;  // f16 elements per chunk
#pragma unroll
  for (int j = 0; j < 4; ++j) {
    const int Rb = wave * 4096 + j * 1024;  // LDS byte offset of this region
    if (wave < 2) {
      const int key = (Rb >> 7) + sRow8;  // 0..63
      sp[j] = kT + ((size_t)(head << 12) + keybase + key) * DH + ((sCol ^ (key & 7)) << 3);
    } else {
      const int dd = ((Rb - 8192) >> 7) + sRow8;  // 0..63
      sp[j] = vv + ((size_t)(head * DH) + dd) * NPIX + keybase + ((sCol ^ (dd & 7)) << 3);
    }
  }
  auto stage = [&](int b) {
    char* base = (char*)(&KV[b][0]) + wave * 4096;
#pragma unroll
    for (int j = 0; j < 4; ++j) {
      gload_lds16(sp[j], base + j * 1024);
      sp[j] += step;
    }
  };

  stage(0);
  __syncthreads();

  for (int ch = 0; ch < 16; ++ch) {
    const int b = ch & 1;
    if (ch < 15) stage(b ^ 1);  // issue early; drains under compute
    const f16* Kb = &KV[b][0];
    const f16* Vb = &KV[b][4096];
#pragma unroll
    for (int h = 0; h < 2; ++h) {  // two 32-key iterations per chunk
      f16x8 kf[2][2], vf[4];
#pragma unroll
      for (int nc = 0; nc < 2; ++nc) {
        const int key = h * 32 + nc * 16 + l15;
#pragma unroll
        for (int kc = 0; kc < 2; ++kc)
          kf[nc][kc] = *(const f16x8*)(Kb + key * 64 + (((kc * 4 + quad) ^ rx) << 3));
      }
#pragma unroll
      for (int c = 0; c < 4; ++c) {
        const int dd = c * 16 + l15;
        vf[c] = *(const f16x8*)(Vb + dd * 64 + (((h * 4 + quad) ^ rx) << 3));
      }
#pragma unroll
      for (int qt = 0; qt < 2; ++qt) {
        // S^T[key][q] = K @ Q'^T (q pre-scaled; C-layout row=key, col=q)
        f32x4 s0 = mfma_f16(kf[0][0], qf[qt][0], (f32x4){0.f, 0.f, 0.f, 0.f});
        s0 = mfma_f16(kf[0][1], qf[qt][1], s0);
        f32x4 s1 = mfma_f16(kf[1][0], qf[qt][0], (f32x4){0.f, 0.f, 0.f, 0.f});
        s1 = mfma_f16(kf[1][1], qf[qt][1], s1);
        // p = exp2(s'), no max subtraction (|s'| << 1)
        float p0[4], p1[4];
#pragma unroll
        for (int r = 0; r < 4; ++r) {
          p0[r] = __builtin_amdgcn_exp2f(s0[r]);
          p1[r] = __builtin_amdgcn_exp2f(s1[r]);
        }
        // per-lane lsum partial; quad-reduce deferred to epilogue
        ol[qt] += ((p0[0] + p0[1]) + (p0[2] + p0[3])) +
                  ((p1[0] + p1[1]) + (p1[2] + p1[3]));
        // P^T C-layout -> B-frag, pure VALU (lane-equivalent to the old
        // 4x ds_bpermute network; r5-verified correct, conflicts -> 0):
        unsigned A0 = pk2(p0[0], p0[1]), B0 = pk2(p0[2], p0[3]);
        unsigned A1 = pk2(p1[0], p1[1]), B1 = pk2(p1[2], p1[3]);
        asm("v_permlane16_swap_b32 %0, %1" : "+v"(A0), "+v"(A1));
        asm("v_permlane16_swap_b32 %0, %1" : "+v"(B0), "+v"(B1));
        unsigned xa = A0, ya = A0;
        asm("v_permlane32_swap_b32 %0, %1" : "+v"(xa), "+v"(ya));
        unsigned xa2 = A1, ya2 = A1;
        asm("v_permlane32_swap_b32 %0, %1" : "+v"(xa2), "+v"(ya2));
        unsigned xb = B0, yb = B0;
        asm("v_permlane32_swap_b32 %0, %1" : "+v"(xb), "+v"(yb));
        unsigned xb2 = B1, yb2 = B1;
        asm("v_permlane32_swap_b32 %0, %1" : "+v"(xb2), "+v"(yb2));
        union { f16x8 v; unsigned u[4]; } pf;
        pf.u[0] = qodd ? ya : xa;
        pf.u[1] = qodd ? yb : xb;
        pf.u[2] = qodd ? ya2 : xa2;
        pf.u[3] = qodd ? yb2 : xb2;
        // O^T[d][q] += V^T @ P^T
#pragma unroll
        for (int c = 0; c < 4; ++c) o[qt][c] = mfma_f16(vf[c], pf.v, o[qt][c]);
      }
    }
    __syncthreads();  // staged writes visible + all waves done with buf b
  }

  // deferred lsum quad-reduce
#pragma unroll
  for (int qt = 0; qt < 2; ++qt) {
    ol[qt] += __shfl_xor(ol[qt], 16);
    ol[qt] += __shfl_xor(ol[qt], 32);
  }

  // store partials (f16): Opart[split][qinst][d], Lpart[split][qinst]
#pragma unroll
  for (int qt = 0; qt < 2; ++qt) {
#pragma unroll
    for (int c = 0; c < 4; ++c) {
      const size_t off =
          ((size_t)split * 32768 + qrow + qt * 16 + l15) * 64 + c * 16 + quad * 4;
      f16x4 hv = {(f16)o[qt][c][0], (f16)o[qt][c][1], (f16)o[qt][c][2],
                  (f16)o[qt][c][3]};
      *(f16x4*)(Opart + off) = hv;
    }
    if (quad == 0) Lpart[split * 32768 + qrow + qt * 16 + l15] = ol[qt];
  }
}

// ---------------- K3b: merge 4 key-split f16 partials ----------------
// 131072 threads; thread tg owns elems [tg*16, +16) of each split plane
// (= qinst tg>>2, d-block (tg&3)*16) -> coalesced 16B loads / 16B stores.
__global__ __launch_bounds__(256) void k_merge(const f16* __restrict__ Opart,
                                               const float* __restrict__ Lpart,
                                               f16* __restrict__ Ows) {
  const int tg = blockIdx.x * 256 + threadIdx.x;
  const int qi = tg >> 2;
  const size_t base = (size_t)tg * 16;
  float acc[16];
#pragma unroll
  for (int i = 0; i < 16; ++i) acc[i] = 0.f;
  float L = 0.f;
#pragma unroll
  for (int s = 0; s < 4; ++s) {
    const f16x8* ph = (const f16x8*)(Opart + (size_t)s * (32768 * 64) + base);
    f16x8 v0 = ph[0], v1 = ph[1];
#pragma unroll
    for (int i = 0; i < 8; ++i) {
      acc[i] += (float)v0[i];
      acc[8 + i] += (float)v1[i];
    }
    L += Lpart[s * 32768 + qi];
  }
  const float rL = 1.0f / L;
  union { f16x8 v[2]; f16 h[16]; } hv;
#pragma unroll
  for (int i = 0; i < 16; ++i) hv.h[i] = (f16)(acc[i] * rL);
  *(f16x8*)(Ows + base) = hv.v[0];
  *(f16x8*)(Ows + base + 8) = hv.v[1];
}

// ---------------- K4: out projection + bias + residual ----------------
__global__ __launch_bounds__(256) void k_oproj(const f16* __restrict__ wout,
                                               const f16* __restrict__ Ows,
                                               const float* __restrict__ bout,
                                               const float* __restrict__ xn,
                                               float* __restrict__ out) {
  const int lane = threadIdx.x & 63, wave = threadIdx.x >> 6;
  const int l15 = lane & 15, quad = lane >> 4;
  const int mbase = blockIdx.y * 32 + (wave >> 1) * 16;
  const int pbase = blockIdx.x * 64 + (wave & 1) * 32;
  f32x4 acc[2];
  acc[0] = (f32x4){0.f, 0.f, 0.f, 0.f};
  acc[1] = (f32x4){0.f, 0.f, 0.f, 0.f};
#pragma unroll
  for (int kc = 0; kc < INNER / 32; ++kc) {
    f16x8 af = *(const f16x8*)(wout + (size_t)(mbase + l15) * INNER + kc * 32 + quad * 8);
    int i0 = kc * 32 + quad * 8;
    int head = i0 >> 6, d0 = i0 & 63;
#pragma unroll
    for (int pc = 0; pc < 2; ++pc) {
      f16x8 bfr = *(const f16x8*)(Ows + ((size_t)(head << 12) + pbase + pc * 16 + l15) * DH + d0);
      acc[pc] = mfma_f16(af, bfr, acc[pc]);
    }
  }
#pragma unroll
  for (int pc = 0; pc < 2; ++pc)
#pragma unroll
    for (int r = 0; r < 4; ++r) {
      int c = mbase + quad * 4 + r, p = pbase + pc * 16 + l15;
      out[c * NPIX + p] = acc[pc][r] + bout[c] + xn[c * NPIX + p];
    }
}

extern "C" void kernel_launch(void* const* d_in, const int* in_sizes, int n_in,
                              void* d_out, int out_size, void* d_ws, size_t ws_size,
                              hipStream_t stream) {
  (void)in_sizes; (void)n_in; (void)out_size; (void)ws_size;
  const float* x      = (const float*)d_in[0];
  const float* norm_w = (const float*)d_in[1];
  const float* w_qkv  = (const float*)d_in[2];
  const float* w_out  = (const float*)d_in[3];
  const float* b_out  = (const float*)d_in[4];
  float* out = (float*)d_out;

  char* ws = (char*)d_ws;
  float* xn    = (float*)(ws);                 // 4 MB
  f16* xnT     = (f16*)(ws + (4u << 20));      // 2 MB
  f16* qT      = (f16*)(ws + (6u << 20));      // 4 MB  [head][p][d], pre-scaled
  f16* kT      = (f16*)(ws + (10u << 20));     // 4 MB  [head][p][d]
  f16* vv      = (f16*)(ws + (14u << 20));     // 4 MB  [head*64+d][p]
  f16* Ows     = (f16*)(ws + (18u << 20));     // 4 MB  [head][p][d]
  f16* wqkv_h  = (f16*)(ws + (22u << 20));             // 0.75 MB
  f16* wout_h  = (f16*)(ws + (22u << 20) + 786432);    // 0.25 MB
  f16* Opart   = (f16*)(ws + (24u << 20));             // 16 MB [4][32768][64]
  float* Lpart = (float*)(ws + (40u << 20));           // 0.5 MB [4][32768]

  const int n1 = 3 * INNER * CIN, n2 = CIN * INNER;
  hipLaunchKernelGGL(k_prep, dim3(NPIX / 8 + (n1 + n2 + 255) / 256), dim3(256), 0,
                     stream, x, norm_w, xn, xnT, w_qkv, n1, w_out, n2, wqkv_h);
  hipLaunchKernelGGL(k_qkv, dim3(NPIX / 128, 1536 / 64), dim3(256), 0, stream,
                     wqkv_h, xnT, qT, kT, vv);
  hipLaunchKernelGGL(k_attn, dim3(1024), dim3(256), 0, stream,
                     qT, kT, vv, Opart, Lpart);
  hipLaunchKernelGGL(k_merge, dim3(512), dim3(256), 0, stream, Opart, Lpart, Ows);
  hipLaunchKernelGGL(k_oproj, dim3(NPIX / 64, CIN / 32), dim3(256), 0, stream,
                     wout_h, Ows, b_out, xn, out);
}